// Round 7
// baseline (627.155 us; speedup 1.0000x reference)
//
#include <hip/hip_runtime.h>
#include <stdint.h>

// Pipeline:
// img (8,160,240,3) -> conv1 6x6 (+fused 2x2 pool) -> (8,77,117,32)
// -> conv2 3x3 (+fused 2x2 pool) -> (8,37,57,64)
// -> conv3 3x3 -> (8,35,55,128) -> flatten 246400 -> dense 256 -> dense 38400
// -> transform -> pred (8,40,60,16); NMS -> keep (8,3,4800)

static __device__ __forceinline__ float sigmoidf_(float x) {
  return 1.0f / (1.0f + expf(-x));
}

// ---------------- conv1 6x6x3->32 + fused 2x2 maxpool ----------------
__global__ __launch_bounds__(256) void k_conv1p(const float* __restrict__ in,
    const float* __restrict__ w, const float* __restrict__ bias, float* __restrict__ out) {
  __shared__ float s_in[21 * 37 * 3];    // [y][x][c]
  __shared__ float s_w[6 * 6 * 3 * 32];  // [ky][kx][c][o]
  int tx = blockIdx.x, ty = blockIdx.y, n = blockIdx.z;
  int tid = threadIdx.x;
  int iy0 = ty * 16, ix0 = tx * 32;
  for (int idx = tid; idx < 3456; idx += 256) s_w[idx] = w[idx];
  for (int idx = tid; idx < 21 * 37 * 3; idx += 256) {
    int c = idx % 3;
    int rem = idx / 3;
    int x = rem % 37, y = rem / 37;
    int gy = iy0 + y, gx = ix0 + x;
    float v = 0.f;
    if (gy < 160 && gx < 240) v = in[((size_t)(n * 160 + gy) * 240 + gx) * 3 + c];
    s_in[idx] = v;
  }
  __syncthreads();

  int cg = tid >> 6;
  int l = tid & 63;
  int py = l >> 2;
  int px0 = (l & 3) * 8;

  float acc[8][8];
  float bj[8];
#pragma unroll
  for (int j = 0; j < 8; j++) bj[j] = bias[cg * 8 + j];
#pragma unroll
  for (int k = 0; k < 8; k++)
#pragma unroll
    for (int j = 0; j < 8; j++) acc[k][j] = bj[j];

#pragma unroll 1
  for (int ky = 0; ky < 6; ky++) {
#pragma unroll 1
    for (int kx = 0; kx < 6; kx++) {
#pragma unroll 1
      for (int c = 0; c < 3; c++) {
        const float* ib = s_in + ((py + ky) * 37 + px0 + kx) * 3 + c;
        float iv[8];
#pragma unroll
        for (int k = 0; k < 8; k++) iv[k] = ib[k * 3];
        const float* wb = s_w + ((ky * 6 + kx) * 3 + c) * 32 + cg * 8;
        float wv[8];
#pragma unroll
        for (int j = 0; j < 8; j++) wv[j] = wb[j];
#pragma unroll
        for (int k = 0; k < 8; k++)
#pragma unroll
          for (int j = 0; j < 8; j++) acc[k][j] = fmaf(iv[k], wv[j], acc[k][j]);
      }
    }
  }
  float pm[4][8];
#pragma unroll
  for (int kk = 0; kk < 4; kk++)
#pragma unroll
    for (int j = 0; j < 8; j++) pm[kk][j] = fmaxf(acc[2 * kk][j], acc[2 * kk + 1][j]);
#pragma unroll
  for (int kk = 0; kk < 4; kk++)
#pragma unroll
    for (int j = 0; j < 8; j++) {
      float o = __shfl_down(pm[kk][j], 4);
      pm[kk][j] = fmaxf(pm[kk][j], o);
    }
  if (!(py & 1)) {
    int pyp = ty * 8 + (py >> 1);
    if (pyp < 77) {
#pragma unroll
      for (int kk = 0; kk < 4; kk++) {
        int pxp = tx * 16 + (l & 3) * 4 + kk;
        if (pxp < 117) {
          float* op = out + ((size_t)(n * 77 + pyp) * 117 + pxp) * 32 + cg * 8;
          float4 v0, v1;
          v0.x = fmaxf(pm[kk][0], 0.f); v0.y = fmaxf(pm[kk][1], 0.f);
          v0.z = fmaxf(pm[kk][2], 0.f); v0.w = fmaxf(pm[kk][3], 0.f);
          v1.x = fmaxf(pm[kk][4], 0.f); v1.y = fmaxf(pm[kk][5], 0.f);
          v1.z = fmaxf(pm[kk][6], 0.f); v1.w = fmaxf(pm[kk][7], 0.f);
          ((float4*)op)[0] = v0;
          ((float4*)op)[1] = v1;
        }
      }
    }
  }
}

// ---------------- conv2 3x3x32->64 + fused 2x2 maxpool ----------------
__global__ __launch_bounds__(128) void k_conv2p(const float* __restrict__ in,
    const float* __restrict__ w, const float* __restrict__ bias, float* __restrict__ out) {
  __shared__ float s_in[32 * 10 * 18];  // [c][y][x]
  int tx = blockIdx.x, ty = blockIdx.y, n = blockIdx.z;
  int tid = threadIdx.x;
  int iy0 = ty * 8, ix0 = tx * 16;
  for (int idx = tid; idx < 10 * 18 * 32; idx += 128) {
    int c = idx & 31;
    int rem = idx >> 5;
    int x = rem % 18, y = rem / 18;
    int gy = iy0 + y, gx = ix0 + x;
    float v = 0.f;
    if (gy < 77 && gx < 117) v = in[((size_t)(n * 77 + gy) * 117 + gx) * 32 + c];
    s_in[c * 180 + y * 18 + x] = v;
  }
  __syncthreads();

  int cg = tid >> 4;
  int pg = tid & 15;
  int py = pg >> 1;
  int px0 = (pg & 1) * 8;

  float acc[8][8];
  float bj[8];
#pragma unroll
  for (int j = 0; j < 8; j++) bj[j] = bias[cg * 8 + j];
#pragma unroll
  for (int k = 0; k < 8; k++)
#pragma unroll
    for (int j = 0; j < 8; j++) acc[k][j] = bj[j];

#pragma unroll 1
  for (int ky = 0; ky < 3; ky++) {
#pragma unroll 1
    for (int kx = 0; kx < 3; kx++) {
      const float* wbase = w + (size_t)((ky * 3 + kx) * 32) * 64 + cg * 8;
      const float* ibase = s_in + (py + ky) * 18 + px0 + kx;
#pragma unroll 4
      for (int c = 0; c < 32; c++) {
        float4 wa = *(const float4*)(wbase + (size_t)c * 64);
        float4 wb = *(const float4*)(wbase + (size_t)c * 64 + 4);
        const float* ib = ibase + c * 180;
        float iv[8];
#pragma unroll
        for (int k = 0; k < 8; k++) iv[k] = ib[k];
#pragma unroll
        for (int k = 0; k < 8; k++) {
          acc[k][0] = fmaf(iv[k], wa.x, acc[k][0]);
          acc[k][1] = fmaf(iv[k], wa.y, acc[k][1]);
          acc[k][2] = fmaf(iv[k], wa.z, acc[k][2]);
          acc[k][3] = fmaf(iv[k], wa.w, acc[k][3]);
          acc[k][4] = fmaf(iv[k], wb.x, acc[k][4]);
          acc[k][5] = fmaf(iv[k], wb.y, acc[k][5]);
          acc[k][6] = fmaf(iv[k], wb.z, acc[k][6]);
          acc[k][7] = fmaf(iv[k], wb.w, acc[k][7]);
        }
      }
    }
  }
  float pm[4][8];
#pragma unroll
  for (int kk = 0; kk < 4; kk++)
#pragma unroll
    for (int j = 0; j < 8; j++) pm[kk][j] = fmaxf(acc[2 * kk][j], acc[2 * kk + 1][j]);
#pragma unroll
  for (int kk = 0; kk < 4; kk++)
#pragma unroll
    for (int j = 0; j < 8; j++) {
      float o = __shfl_down(pm[kk][j], 2);
      pm[kk][j] = fmaxf(pm[kk][j], o);
    }
  if (!(pg & 2)) {
    int pyp = ty * 4 + (py >> 1);
    if (pyp < 37) {
#pragma unroll
      for (int kk = 0; kk < 4; kk++) {
        int pxp = tx * 8 + (pg & 1) * 4 + kk;
        if (pxp < 57) {
          float* op = out + ((size_t)(n * 37 + pyp) * 57 + pxp) * 64 + cg * 8;
          float4 v0, v1;
          v0.x = fmaxf(pm[kk][0], 0.f); v0.y = fmaxf(pm[kk][1], 0.f);
          v0.z = fmaxf(pm[kk][2], 0.f); v0.w = fmaxf(pm[kk][3], 0.f);
          v1.x = fmaxf(pm[kk][4], 0.f); v1.y = fmaxf(pm[kk][5], 0.f);
          v1.z = fmaxf(pm[kk][6], 0.f); v1.w = fmaxf(pm[kk][7], 0.f);
          ((float4*)op)[0] = v0;
          ((float4*)op)[1] = v1;
        }
      }
    }
  }
}

// ---------------- conv3: 3x3x64 -> 128, channel-split x2 ----------------
__global__ __launch_bounds__(256) void k_conv3(const float* __restrict__ in,
    const float* __restrict__ w, const float* __restrict__ bias, float* __restrict__ out) {
  __shared__ float s_in[64 * 10 * 18];  // [c][y][x]
  int tx = blockIdx.x, ty = blockIdx.y, z = blockIdx.z;
  int n = z >> 1, h = z & 1;
  int tid = threadIdx.x;
  int iy0 = ty * 8, ix0 = tx * 16;
  for (int idx = tid; idx < 10 * 18 * 64; idx += 256) {
    int c = idx & 63;
    int rem = idx >> 6;
    int x = rem % 18, y = rem / 18;
    int gy = iy0 + y, gx = ix0 + x;
    float v = 0.f;
    if (gy < 37 && gx < 57) v = in[((size_t)(n * 37 + gy) * 57 + gx) * 64 + c];
    s_in[c * 180 + y * 18 + x] = v;
  }
  __syncthreads();

  int cg = tid >> 4;
  int pg = tid & 15;
  int py = pg >> 1;
  int px0 = (pg & 1) * 8;
  int ob = h * 64 + cg * 4;

  float acc[8][4];
  float bj[4];
#pragma unroll
  for (int j = 0; j < 4; j++) bj[j] = bias[ob + j];
#pragma unroll
  for (int k = 0; k < 8; k++)
#pragma unroll
    for (int j = 0; j < 4; j++) acc[k][j] = bj[j];

#pragma unroll 1
  for (int ky = 0; ky < 3; ky++) {
#pragma unroll 1
    for (int kx = 0; kx < 3; kx++) {
      const float* wbase = w + (size_t)((ky * 3 + kx) * 64) * 128 + ob;
      const float* ibase = s_in + (py + ky) * 18 + px0 + kx;
#pragma unroll 4
      for (int c = 0; c < 64; c++) {
        float4 wa = *(const float4*)(wbase + (size_t)c * 128);
        const float* ib = ibase + c * 180;
        float iv[8];
#pragma unroll
        for (int k = 0; k < 8; k++) iv[k] = ib[k];
#pragma unroll
        for (int k = 0; k < 8; k++) {
          acc[k][0] = fmaf(iv[k], wa.x, acc[k][0]);
          acc[k][1] = fmaf(iv[k], wa.y, acc[k][1]);
          acc[k][2] = fmaf(iv[k], wa.z, acc[k][2]);
          acc[k][3] = fmaf(iv[k], wa.w, acc[k][3]);
        }
      }
    }
  }
  int oy = iy0 + py;
  if (oy < 35) {
#pragma unroll
    for (int k = 0; k < 8; k++) {
      int ox = ix0 + px0 + k;
      if (ox < 55) {
        float* op = out + ((size_t)(n * 35 + oy) * 55 + ox) * 128 + ob;
        float4 v0;
        v0.x = fmaxf(acc[k][0], 0.f); v0.y = fmaxf(acc[k][1], 0.f);
        v0.z = fmaxf(acc[k][2], 0.f); v0.w = fmaxf(acc[k][3], 0.f);
        ((float4*)op)[0] = v0;
      }
    }
  }
}

// ---------------- dense1: (8,246400) @ (246400,256), split-K partials ----------------
__global__ __launch_bounds__(256) void k_dense1(const float* __restrict__ a3,
    const float* __restrict__ wd1, float* __restrict__ part) {
  __shared__ float red[4][64][32];
  int c = blockIdx.x;
  int tid = threadIdx.x;
  int c4 = tid & 63;
  int ks = tid >> 6;
  int k0 = c * 256;
  int kn = 246400 - k0;
  if (kn > 256) kn = 256;
  float acc[8][4];
#pragma unroll
  for (int n = 0; n < 8; n++)
#pragma unroll
    for (int j = 0; j < 4; j++) acc[n][j] = 0.f;
  int kbeg = ks * 64;
  int kend = kbeg + 64;
  if (kend > kn) kend = kn;
#pragma unroll 1
  for (int kk = kbeg; kk < kend; kk++) {
    size_t row = (size_t)(k0 + kk);
    float4 wv = *(const float4*)(wd1 + row * 256 + c4 * 4);
    float xs[8];
#pragma unroll
    for (int n = 0; n < 8; n++) xs[n] = a3[(size_t)n * 246400 + row];
#pragma unroll
    for (int n = 0; n < 8; n++) {
      acc[n][0] = fmaf(xs[n], wv.x, acc[n][0]);
      acc[n][1] = fmaf(xs[n], wv.y, acc[n][1]);
      acc[n][2] = fmaf(xs[n], wv.z, acc[n][2]);
      acc[n][3] = fmaf(xs[n], wv.w, acc[n][3]);
    }
  }
#pragma unroll
  for (int n = 0; n < 8; n++)
#pragma unroll
    for (int j = 0; j < 4; j++) red[ks][c4][n * 4 + j] = acc[n][j];
  __syncthreads();
  for (int o = tid; o < 2048; o += 256) {
    int col = o & 255, n = o >> 8;
    int cc = col >> 2, j = col & 3;
    float s = red[0][cc][n * 4 + j] + red[1][cc][n * 4 + j] +
              red[2][cc][n * 4 + j] + red[3][cc][n * 4 + j];
    part[(size_t)c * 2048 + n * 256 + col] = s;
  }
}

// ---------------- reduce1 stage A/B ----------------
__global__ __launch_bounds__(256) void k_reduce1a(const float* __restrict__ part,
    float* __restrict__ partr) {
  int bx = blockIdx.x;
  int t = blockIdx.y * 256 + threadIdx.x;
  int cbeg = bx * 61;
  int cend = cbeg + 61;
  if (cend > 963) cend = 963;
  float s = 0.f;
  for (int c = cbeg; c < cend; c++) s += part[(size_t)c * 2048 + t];
  partr[(size_t)bx * 2048 + t] = s;
}

__global__ __launch_bounds__(256) void k_reduce1b(const float* __restrict__ partr,
    const float* __restrict__ bd1, float* __restrict__ d1t) {
  int t = blockIdx.x * 256 + threadIdx.x;
  if (t >= 2048) return;
  float s = 0.f;
#pragma unroll
  for (int b = 0; b < 16; b++) s += partr[(size_t)b * 2048 + t];
  int n = t >> 8, j = t & 255;
  float v = s + bd1[j];
  d1t[j * 8 + n] = fmaxf(v, 0.f);
}

// ---------------- dense2 full-K fused: (8,256) @ (256,38400) + bias ----------------
__global__ __launch_bounds__(256) void k_dense2f(const float* __restrict__ d1t,
    const float* __restrict__ wd2, const float* __restrict__ bd2, float* __restrict__ d2) {
  __shared__ float red[4][64][32];
  int jb = blockIdx.x;
  int tid = threadIdx.x;
  int c4 = tid & 63;
  int ks = tid >> 6;
  int j0 = jb * 256 + c4 * 4;
  float acc[8][4];
#pragma unroll
  for (int n = 0; n < 8; n++)
#pragma unroll
    for (int j = 0; j < 4; j++) acc[n][j] = 0.f;
#pragma unroll 1
  for (int kk = 0; kk < 64; kk++) {
    int row = ks * 64 + kk;
    float4 wv = *(const float4*)(wd2 + (size_t)row * 38400 + j0);
    float4 xa = *(const float4*)(d1t + row * 8);
    float4 xb = *(const float4*)(d1t + row * 8 + 4);
    float xs[8] = {xa.x, xa.y, xa.z, xa.w, xb.x, xb.y, xb.z, xb.w};
#pragma unroll
    for (int n = 0; n < 8; n++) {
      acc[n][0] = fmaf(xs[n], wv.x, acc[n][0]);
      acc[n][1] = fmaf(xs[n], wv.y, acc[n][1]);
      acc[n][2] = fmaf(xs[n], wv.z, acc[n][2]);
      acc[n][3] = fmaf(xs[n], wv.w, acc[n][3]);
    }
  }
#pragma unroll
  for (int n = 0; n < 8; n++)
#pragma unroll
    for (int j = 0; j < 4; j++) red[ks][c4][n * 4 + j] = acc[n][j];
  __syncthreads();
  for (int o = tid; o < 2048; o += 256) {
    int col = o & 255, n = o >> 8;
    int cc = col >> 2, j = col & 3;
    float s = red[0][cc][n * 4 + j] + red[1][cc][n * 4 + j] +
              red[2][cc][n * 4 + j] + red[3][cc][n * 4 + j] + bd2[jb * 256 + col];
    d2[(size_t)n * 38400 + jb * 256 + col] = s;
  }
}

// ---------------- transform + keep-zero fused ----------------
__global__ __launch_bounds__(256) void k_transform(const float* __restrict__ d2,
    float* __restrict__ pred, float* __restrict__ boxd, float* __restrict__ keep_out) {
  int t = blockIdx.x * 256 + threadIdx.x;
  if (t < 115200) keep_out[t] = 0.f;
  if (t >= 19200) return;
  int cell = t % 2400;
  int n = t / 2400;
  float gx = (float)(cell % 60), gy = (float)(cell / 60);
  const float* p = d2 + (size_t)t * 16;
  float o[16];
  o[0] = (sigmoidf_(p[0]) + gx) * 4.0f;
  o[1] = (sigmoidf_(p[1]) + gy) * 4.0f;
  o[2] = expf(p[2]) * 60.0f * 4.0f;
  o[3] = expf(p[3]) * 30.0f * 4.0f;
  o[4] = sigmoidf_(p[4]);
  o[5] = sigmoidf_(p[5]);
  o[6] = sigmoidf_(p[6]);
  o[7] = sigmoidf_(p[7]);
  o[8] = (p[8] + gx) * 4.0f;
  o[9] = (p[9] + gy) * 4.0f;
  o[10] = expf(p[10]) * 20.0f * 4.0f;
  o[11] = expf(p[11]) * 40.0f * 4.0f;
  o[12] = p[12];
  o[13] = sigmoidf_(p[13]);
  o[14] = sigmoidf_(p[14]);
  o[15] = sigmoidf_(p[15]);
  float* op = pred + (size_t)t * 16;
#pragma unroll
  for (int q = 0; q < 16; q++) op[q] = o[q];
#pragma unroll
  for (int h = 0; h < 2; h++) {
    int b = n * 4800 + h * 2400 + cell;
    float X = o[h * 8 + 0], Y = o[h * 8 + 1], W = o[h * 8 + 2], H = o[h * 8 + 3];
    float conf = o[h * 8 + 4];
    float c0 = o[h * 8 + 5], c1 = o[h * 8 + 6], c2 = o[h * 8 + 7];
    int cls = 0; float best = c0;
    if (c1 > best) { best = c1; cls = 1; }
    if (c2 > best) { best = c2; cls = 2; }
    float x1 = X - W / 2.0f, y1 = Y - H / 2.0f;
    float x2 = X + W / 2.0f, y2 = Y + H / 2.0f;
    float area = (x2 - x1 + 1.0f) * (y2 - y1 + 1.0f);
    float* bp2 = boxd + (size_t)b * 8;
    bp2[0] = x1; bp2[1] = y1; bp2[2] = x2; bp2[3] = y2;
    bp2[4] = area; bp2[5] = conf;
    ((int*)bp2)[6] = cls; bp2[7] = 0.f;
  }
}

// ---------------- NMS: one block per (image, class), LDS-resident ----------------
// compact -> bitonic sort -> (V<=1024 fast path) build suppression bit-matrix in
// LDS with all 4 waves (ballot per 64-col word), then wave-0 linear greedy scan:
// alive(i) ? { keep; avail &= ~mat[i] } : skip.  (V>1024 fallback = prior greedy.)
__global__ __launch_bounds__(256) void k_nms(const float* __restrict__ boxd,
    float* __restrict__ keep_out) {
  __shared__ unsigned long long buf64[18960];  // 151,680 B, manually partitioned
  __shared__ int scnt;
  int bid = blockIdx.x;  // 0..23
  int n = bid / 3, c = bid - n * 3;
  int tid = threadIdx.x;
  int l = tid & 63, wv = tid >> 6;
  const float* bd = boxd + (size_t)n * 4800 * 8;
  unsigned long long* key = buf64;  // [0, 65536 B): compaction (<=4800) + sort (<=8192)
  if (tid == 0) scnt = 0;
  __syncthreads();

  // ---- compact ----
  for (int p = tid; p < 4800; p += 256) {
    const float* bp = bd + (size_t)p * 8;
    float conf = bp[5];
    int cls = ((const int*)bp)[6];
    if (conf > 0.5f && cls == c) {
      int slot = atomicAdd(&scnt, 1);
      unsigned u = __float_as_uint(conf);
      unsigned asc = (u & 0x80000000u) ? ~u : (u | 0x80000000u);
      key[slot] = (((unsigned long long)(~asc)) << 32) | (unsigned)p;
    }
  }
  __syncthreads();
  int V = scnt;
  if (V == 0) return;
  int Vp2 = 1;
  while (Vp2 < V) Vp2 <<= 1;
  for (int s = V + tid; s < Vp2; s += 256) key[s] = ~0ull;

  // ---- bitonic sort ascending -> score desc, idx asc (stable argsort(-score)) ----
  for (int k = 2; k <= Vp2; k <<= 1) {
    for (int j = k >> 1; j > 0; j >>= 1) {
      __syncthreads();
      int jm = j - 1;
      for (int t2 = tid; t2 < (Vp2 >> 1); t2 += 256) {
        int i = ((t2 & ~jm) << 1) | (t2 & jm);
        int q = i | j;
        bool up = ((i & k) == 0);
        unsigned long long a = key[i], b2 = key[q];
        if ((a > b2) == up) { key[i] = b2; key[q] = a; }
      }
    }
  }
  __syncthreads();
  float* ko = keep_out + (size_t)bid * 4800;

  if (V <= 1024) {
    // ======== fast path: bit-matrix + linear scan ========
    int W = (V + 63) >> 6;                               // <= 16 words/row
    unsigned long long* mat = buf64;                     // [0, 131072 B) overwrites key later
    float4* sb = (float4*)(buf64 + 16384);               // byte 131072, 1024 * 16 B
    int* sidx = (int*)(buf64 + 18432);                   // byte 147456, 1024 * 4 B
    unsigned long long* avail = buf64 + 18944;           // byte 151552, 16 words
    for (int s = tid; s < V; s += 256) {
      unsigned long long kk = key[s];
      unsigned p = (unsigned)(kk & 0xFFFFFFFFull);
      const float* bp = bd + (size_t)p * 8;
      sb[s] = make_float4(bp[0], bp[1], bp[2], bp[3]);
      sidx[s] = (int)p;
    }
    __syncthreads();  // key fully consumed; mat may now overwrite it

    // build: wave wv owns word-columns w = wv, wv+4, ...
    for (int w = wv; w < W; w += 4) {
      int col = (w << 6) + l;
      float4 bj = sb[col];  // col < W*64 <= 1024, region valid; col>=V guarded in pr
      float aj = (bj.z - bj.x + 1.0f) * (bj.w - bj.y + 1.0f);
      int rl = (w + 1) << 6;
      if (rl > V) rl = V;
      for (int i = 0; i < V; i++) {
        unsigned long long word = 0;
        if (i < rl) {
          float4 bi = sb[i];  // uniform -> LDS broadcast
          float iw = fminf(bi.z, bj.z) - fmaxf(bi.x, bj.x) + 1.0f;
          float ih = fminf(bi.w, bj.w) - fmaxf(bi.y, bj.y) + 1.0f;
          iw = fmaxf(iw, 0.f);
          ih = fmaxf(ih, 0.f);
          float inter = iw * ih;
          float ai = (bi.z - bi.x + 1.0f) * (bi.w - bi.y + 1.0f);
          float iou = inter / (ai + aj - inter);
          bool pr = (col > i) && (col < V) && (iou >= 0.4f);
          word = __ballot(pr);
        }
        if (l == 0) mat[(size_t)i * W + w] = word;
      }
    }
    __syncthreads();
    if (wv != 0) return;

    // wave-0 linear greedy scan (same-wave LDS ops are ordered)
    if (l < 16) {
      int rem = V - (l << 6);
      avail[l] = (rem >= 64) ? ~0ull : (rem <= 0 ? 0ull : ((1ull << rem) - 1ull));
    }
    for (int i = 0; i < V; i++) {
      unsigned long long aw = avail[i >> 6];  // uniform
      if (!((aw >> (i & 63)) & 1ull)) continue;
      if (l == 0) ko[sidx[i]] = 1.0f;
      if (l < W) {
        unsigned long long m = mat[(size_t)i * W + l];
        avail[l] &= ~m;
      }
    }
    return;
  }

  // ======== slow path (V > 1024): prior validated greedy ========
  {
    float4* sb = (float4*)(buf64 + 8192);        // byte 65536, 4800 * 16 B
    unsigned long long* avail = buf64 + 17792;   // byte 142336, 75 words
    for (int s = tid; s < V; s += 256) {
      unsigned p = (unsigned)(key[s] & 0xFFFFFFFFull);
      const float* bp = bd + (size_t)p * 8;
      sb[s] = make_float4(bp[0], bp[1], bp[2], bp[3]);
    }
    for (int w = tid; w < 75; w += 256) {
      int rem = V - (w << 6);
      avail[w] = (rem >= 64) ? ~0ull : (rem <= 0 ? 0ull : ((1ull << rem) - 1ull));
    }
    __syncthreads();
    if (tid >= 64) return;
    int wlast = (V - 1) >> 6;
    for (;;) {
      int cand = 0x7FFFFFFF;
      unsigned long long a0 = avail[l];
      if (a0) cand = (l << 6) + __ffsll((long long)a0) - 1;
      if (l < 11) {
        unsigned long long a1 = avail[64 + l];
        if (a1) {
          int c2 = ((64 + l) << 6) + __ffsll((long long)a1) - 1;
          if (c2 < cand) cand = c2;
        }
      }
#pragma unroll
      for (int off = 32; off > 0; off >>= 1) {
        int o = __shfl_xor(cand, off, 64);
        if (o < cand) cand = o;
      }
      if (cand == 0x7FFFFFFF) break;
      int i = cand;
      int tw = i >> 6;
      if (l == 0) {
        ko[(unsigned)(key[i] & 0xFFFFFFFFull)] = 1.0f;
        avail[tw] &= ~(1ull << (i & 63));
      }
      float4 bi = sb[i];
      float ai = (bi.z - bi.x + 1.0f) * (bi.w - bi.y + 1.0f);
      for (int w = tw; w <= wlast; w++) {
        unsigned long long aw = avail[w];
        if (!aw) continue;
        int col = (w << 6) + l;
        float4 bj = sb[col];
        float iw = fminf(bi.z, bj.z) - fmaxf(bi.x, bj.x) + 1.0f;
        float ih = fminf(bi.w, bj.w) - fmaxf(bi.y, bj.y) + 1.0f;
        iw = fmaxf(iw, 0.f);
        ih = fmaxf(ih, 0.f);
        float inter = iw * ih;
        float aj = (bj.z - bj.x + 1.0f) * (bj.w - bj.y + 1.0f);
        float iou = inter / (ai + aj - inter);
        bool pr = (col > i) && (col < V) && (iou >= 0.4f);
        unsigned long long word = __ballot(pr);
        if (word && l == 0) avail[w] = aw & ~word;
      }
    }
  }
}

extern "C" void kernel_launch(void* const* d_in, const int* in_sizes, int n_in,
                              void* d_out, int out_size, void* d_ws, size_t ws_size,
                              hipStream_t stream) {
  const float* img = (const float*)d_in[0];
  const float* w1 = (const float*)d_in[1];
  const float* b1 = (const float*)d_in[2];
  const float* w2 = (const float*)d_in[3];
  const float* b2 = (const float*)d_in[4];
  const float* w3 = (const float*)d_in[5];
  const float* b3 = (const float*)d_in[6];
  const float* wd1 = (const float*)d_in[7];
  const float* bd1 = (const float*)d_in[8];
  const float* wd2 = (const float*)d_in[9];
  const float* bd2 = (const float*)d_in[10];

  float* ws = (float*)d_ws;
  float* a3 = ws + 0;                 // 1,971,200
  float* pd1 = ws + 3942400;          // 963*2048 = 1,972,224
  float* partr = ws + 5914624;        // 16*2048
  float* d1t = ws + 5947392;          // 2048
  float* d2 = ws + 5949440;           // 307,200
  float* boxd = ws + 6256640;         // 307,200
  float* p1 = ws + 9324800;           // 2,306,304 pooled conv1
  float* p2 = ws + 16047104;          // 1,079,808 pooled conv2

  float* pred = (float*)d_out;
  float* keep = pred + 307200;

  k_conv1p<<<dim3(8, 10, 8), 256, 0, stream>>>(img, w1, b1, p1);
  k_conv2p<<<dim3(8, 10, 8), 128, 0, stream>>>(p1, w2, b2, p2);
  k_conv3<<<dim3(4, 5, 16), 256, 0, stream>>>(p2, w3, b3, a3);
  k_dense1<<<963, 256, 0, stream>>>(a3, wd1, pd1);
  k_reduce1a<<<dim3(16, 8), 256, 0, stream>>>(pd1, partr);
  k_reduce1b<<<8, 256, 0, stream>>>(partr, bd1, d1t);
  k_dense2f<<<150, 256, 0, stream>>>(d1t, wd2, bd2, d2);
  k_transform<<<450, 256, 0, stream>>>(d2, pred, boxd, keep);
  k_nms<<<24, 256, 0, stream>>>(boxd, keep);
}

// Round 8
// 611.602 us; speedup vs baseline: 1.0254x; 1.0254x over previous
//
#include <hip/hip_runtime.h>
#include <stdint.h>

// Pipeline:
// img (8,160,240,3) -> conv1 6x6 (+fused 2x2 pool) -> (8,77,117,32)
// -> conv2 3x3 (+fused 2x2 pool) -> (8,37,57,64)
// -> conv3 3x3 -> (8,35,55,128) -> flatten 246400 -> dense 256 -> dense 38400
// -> transform -> pred (8,40,60,16); NMS -> keep (8,3,4800)

static __device__ __forceinline__ float sigmoidf_(float x) {
  return 1.0f / (1.0f + expf(-x));
}

// ---------------- conv1 6x6x3->32 + fused 2x2 maxpool ----------------
__global__ __launch_bounds__(256) void k_conv1p(const float* __restrict__ in,
    const float* __restrict__ w, const float* __restrict__ bias, float* __restrict__ out) {
  __shared__ float s_in[21 * 37 * 3];    // [y][x][c]
  __shared__ float s_w[6 * 6 * 3 * 32];  // [ky][kx][c][o]
  int tx = blockIdx.x, ty = blockIdx.y, n = blockIdx.z;
  int tid = threadIdx.x;
  int iy0 = ty * 16, ix0 = tx * 32;
  for (int idx = tid; idx < 3456; idx += 256) s_w[idx] = w[idx];
  for (int idx = tid; idx < 21 * 37 * 3; idx += 256) {
    int c = idx % 3;
    int rem = idx / 3;
    int x = rem % 37, y = rem / 37;
    int gy = iy0 + y, gx = ix0 + x;
    float v = 0.f;
    if (gy < 160 && gx < 240) v = in[((size_t)(n * 160 + gy) * 240 + gx) * 3 + c];
    s_in[idx] = v;
  }
  __syncthreads();

  int cg = tid >> 6;
  int l = tid & 63;
  int py = l >> 2;
  int px0 = (l & 3) * 8;

  float acc[8][8];
  float bj[8];
#pragma unroll
  for (int j = 0; j < 8; j++) bj[j] = bias[cg * 8 + j];
#pragma unroll
  for (int k = 0; k < 8; k++)
#pragma unroll
    for (int j = 0; j < 8; j++) acc[k][j] = bj[j];

#pragma unroll 1
  for (int ky = 0; ky < 6; ky++) {
#pragma unroll 1
    for (int kx = 0; kx < 6; kx++) {
#pragma unroll 1
      for (int c = 0; c < 3; c++) {
        const float* ib = s_in + ((py + ky) * 37 + px0 + kx) * 3 + c;
        float iv[8];
#pragma unroll
        for (int k = 0; k < 8; k++) iv[k] = ib[k * 3];
        const float* wb = s_w + ((ky * 6 + kx) * 3 + c) * 32 + cg * 8;
        float wv[8];
#pragma unroll
        for (int j = 0; j < 8; j++) wv[j] = wb[j];
#pragma unroll
        for (int k = 0; k < 8; k++)
#pragma unroll
          for (int j = 0; j < 8; j++) acc[k][j] = fmaf(iv[k], wv[j], acc[k][j]);
      }
    }
  }
  float pm[4][8];
#pragma unroll
  for (int kk = 0; kk < 4; kk++)
#pragma unroll
    for (int j = 0; j < 8; j++) pm[kk][j] = fmaxf(acc[2 * kk][j], acc[2 * kk + 1][j]);
#pragma unroll
  for (int kk = 0; kk < 4; kk++)
#pragma unroll
    for (int j = 0; j < 8; j++) {
      float o = __shfl_down(pm[kk][j], 4);
      pm[kk][j] = fmaxf(pm[kk][j], o);
    }
  if (!(py & 1)) {
    int pyp = ty * 8 + (py >> 1);
    if (pyp < 77) {
#pragma unroll
      for (int kk = 0; kk < 4; kk++) {
        int pxp = tx * 16 + (l & 3) * 4 + kk;
        if (pxp < 117) {
          float* op = out + ((size_t)(n * 77 + pyp) * 117 + pxp) * 32 + cg * 8;
          float4 v0, v1;
          v0.x = fmaxf(pm[kk][0], 0.f); v0.y = fmaxf(pm[kk][1], 0.f);
          v0.z = fmaxf(pm[kk][2], 0.f); v0.w = fmaxf(pm[kk][3], 0.f);
          v1.x = fmaxf(pm[kk][4], 0.f); v1.y = fmaxf(pm[kk][5], 0.f);
          v1.z = fmaxf(pm[kk][6], 0.f); v1.w = fmaxf(pm[kk][7], 0.f);
          ((float4*)op)[0] = v0;
          ((float4*)op)[1] = v1;
        }
      }
    }
  }
}

// ---------------- conv2 3x3x32->64 + fused 2x2 maxpool ----------------
__global__ __launch_bounds__(128) void k_conv2p(const float* __restrict__ in,
    const float* __restrict__ w, const float* __restrict__ bias, float* __restrict__ out) {
  __shared__ float s_in[32 * 10 * 18];  // [c][y][x]
  int tx = blockIdx.x, ty = blockIdx.y, n = blockIdx.z;
  int tid = threadIdx.x;
  int iy0 = ty * 8, ix0 = tx * 16;
  for (int idx = tid; idx < 10 * 18 * 32; idx += 128) {
    int c = idx & 31;
    int rem = idx >> 5;
    int x = rem % 18, y = rem / 18;
    int gy = iy0 + y, gx = ix0 + x;
    float v = 0.f;
    if (gy < 77 && gx < 117) v = in[((size_t)(n * 77 + gy) * 117 + gx) * 32 + c];
    s_in[c * 180 + y * 18 + x] = v;
  }
  __syncthreads();

  int cg = tid >> 4;
  int pg = tid & 15;
  int py = pg >> 1;
  int px0 = (pg & 1) * 8;

  float acc[8][8];
  float bj[8];
#pragma unroll
  for (int j = 0; j < 8; j++) bj[j] = bias[cg * 8 + j];
#pragma unroll
  for (int k = 0; k < 8; k++)
#pragma unroll
    for (int j = 0; j < 8; j++) acc[k][j] = bj[j];

#pragma unroll 1
  for (int ky = 0; ky < 3; ky++) {
#pragma unroll 1
    for (int kx = 0; kx < 3; kx++) {
      const float* wbase = w + (size_t)((ky * 3 + kx) * 32) * 64 + cg * 8;
      const float* ibase = s_in + (py + ky) * 18 + px0 + kx;
#pragma unroll 4
      for (int c = 0; c < 32; c++) {
        float4 wa = *(const float4*)(wbase + (size_t)c * 64);
        float4 wb = *(const float4*)(wbase + (size_t)c * 64 + 4);
        const float* ib = ibase + c * 180;
        float iv[8];
#pragma unroll
        for (int k = 0; k < 8; k++) iv[k] = ib[k];
#pragma unroll
        for (int k = 0; k < 8; k++) {
          acc[k][0] = fmaf(iv[k], wa.x, acc[k][0]);
          acc[k][1] = fmaf(iv[k], wa.y, acc[k][1]);
          acc[k][2] = fmaf(iv[k], wa.z, acc[k][2]);
          acc[k][3] = fmaf(iv[k], wa.w, acc[k][3]);
          acc[k][4] = fmaf(iv[k], wb.x, acc[k][4]);
          acc[k][5] = fmaf(iv[k], wb.y, acc[k][5]);
          acc[k][6] = fmaf(iv[k], wb.z, acc[k][6]);
          acc[k][7] = fmaf(iv[k], wb.w, acc[k][7]);
        }
      }
    }
  }
  float pm[4][8];
#pragma unroll
  for (int kk = 0; kk < 4; kk++)
#pragma unroll
    for (int j = 0; j < 8; j++) pm[kk][j] = fmaxf(acc[2 * kk][j], acc[2 * kk + 1][j]);
#pragma unroll
  for (int kk = 0; kk < 4; kk++)
#pragma unroll
    for (int j = 0; j < 8; j++) {
      float o = __shfl_down(pm[kk][j], 2);
      pm[kk][j] = fmaxf(pm[kk][j], o);
    }
  if (!(pg & 2)) {
    int pyp = ty * 4 + (py >> 1);
    if (pyp < 37) {
#pragma unroll
      for (int kk = 0; kk < 4; kk++) {
        int pxp = tx * 8 + (pg & 1) * 4 + kk;
        if (pxp < 57) {
          float* op = out + ((size_t)(n * 37 + pyp) * 57 + pxp) * 64 + cg * 8;
          float4 v0, v1;
          v0.x = fmaxf(pm[kk][0], 0.f); v0.y = fmaxf(pm[kk][1], 0.f);
          v0.z = fmaxf(pm[kk][2], 0.f); v0.w = fmaxf(pm[kk][3], 0.f);
          v1.x = fmaxf(pm[kk][4], 0.f); v1.y = fmaxf(pm[kk][5], 0.f);
          v1.z = fmaxf(pm[kk][6], 0.f); v1.w = fmaxf(pm[kk][7], 0.f);
          ((float4*)op)[0] = v0;
          ((float4*)op)[1] = v1;
        }
      }
    }
  }
}

// ---------------- conv3: 3x3x64 -> 128, channel-split x2 ----------------
__global__ __launch_bounds__(256) void k_conv3(const float* __restrict__ in,
    const float* __restrict__ w, const float* __restrict__ bias, float* __restrict__ out) {
  __shared__ float s_in[64 * 10 * 18];  // [c][y][x]
  int tx = blockIdx.x, ty = blockIdx.y, z = blockIdx.z;
  int n = z >> 1, h = z & 1;
  int tid = threadIdx.x;
  int iy0 = ty * 8, ix0 = tx * 16;
  for (int idx = tid; idx < 10 * 18 * 64; idx += 256) {
    int c = idx & 63;
    int rem = idx >> 6;
    int x = rem % 18, y = rem / 18;
    int gy = iy0 + y, gx = ix0 + x;
    float v = 0.f;
    if (gy < 37 && gx < 57) v = in[((size_t)(n * 37 + gy) * 57 + gx) * 64 + c];
    s_in[c * 180 + y * 18 + x] = v;
  }
  __syncthreads();

  int cg = tid >> 4;
  int pg = tid & 15;
  int py = pg >> 1;
  int px0 = (pg & 1) * 8;
  int ob = h * 64 + cg * 4;

  float acc[8][4];
  float bj[4];
#pragma unroll
  for (int j = 0; j < 4; j++) bj[j] = bias[ob + j];
#pragma unroll
  for (int k = 0; k < 8; k++)
#pragma unroll
    for (int j = 0; j < 4; j++) acc[k][j] = bj[j];

#pragma unroll 1
  for (int ky = 0; ky < 3; ky++) {
#pragma unroll 1
    for (int kx = 0; kx < 3; kx++) {
      const float* wbase = w + (size_t)((ky * 3 + kx) * 64) * 128 + ob;
      const float* ibase = s_in + (py + ky) * 18 + px0 + kx;
#pragma unroll 4
      for (int c = 0; c < 64; c++) {
        float4 wa = *(const float4*)(wbase + (size_t)c * 128);
        const float* ib = ibase + c * 180;
        float iv[8];
#pragma unroll
        for (int k = 0; k < 8; k++) iv[k] = ib[k];
#pragma unroll
        for (int k = 0; k < 8; k++) {
          acc[k][0] = fmaf(iv[k], wa.x, acc[k][0]);
          acc[k][1] = fmaf(iv[k], wa.y, acc[k][1]);
          acc[k][2] = fmaf(iv[k], wa.z, acc[k][2]);
          acc[k][3] = fmaf(iv[k], wa.w, acc[k][3]);
        }
      }
    }
  }
  int oy = iy0 + py;
  if (oy < 35) {
#pragma unroll
    for (int k = 0; k < 8; k++) {
      int ox = ix0 + px0 + k;
      if (ox < 55) {
        float* op = out + ((size_t)(n * 35 + oy) * 55 + ox) * 128 + ob;
        float4 v0;
        v0.x = fmaxf(acc[k][0], 0.f); v0.y = fmaxf(acc[k][1], 0.f);
        v0.z = fmaxf(acc[k][2], 0.f); v0.w = fmaxf(acc[k][3], 0.f);
        ((float4*)op)[0] = v0;
      }
    }
  }
}

// ---------------- dense1: (8,246400) @ (246400,256), split-K, x staged in LDS ----------------
__global__ __launch_bounds__(256) void k_dense1(const float* __restrict__ a3,
    const float* __restrict__ wd1, float* __restrict__ part) {
  __shared__ float red[4][64][32];
  __shared__ float s_x[256][8];
  int c = blockIdx.x;
  int tid = threadIdx.x;
  int c4 = tid & 63;
  int ks = tid >> 6;
  int k0 = c * 256;
  int kn = 246400 - k0;
  if (kn > 256) kn = 256;
  // stage x[row][n]; iteration j covers n=j, r=tid (coalesced per n)
  for (int idx = tid; idx < 2048; idx += 256) {
    int nn = idx >> 8, r = idx & 255;
    int rr = k0 + r;
    if (rr > 246399) rr = 246399;
    s_x[r][nn] = a3[(size_t)nn * 246400 + rr];
  }
  __syncthreads();
  float acc[8][4];
#pragma unroll
  for (int n = 0; n < 8; n++)
#pragma unroll
    for (int j = 0; j < 4; j++) acc[n][j] = 0.f;
  int kbeg = ks * 64;
  int kend = kbeg + 64;
  if (kend > kn) kend = kn;
#pragma unroll 1
  for (int kk = kbeg; kk < kend; kk++) {
    float4 wv = *(const float4*)(wd1 + (size_t)(k0 + kk) * 256 + c4 * 4);
    float4 xa = *(const float4*)&s_x[kk][0];
    float4 xb = *(const float4*)&s_x[kk][4];
    float xs[8] = {xa.x, xa.y, xa.z, xa.w, xb.x, xb.y, xb.z, xb.w};
#pragma unroll
    for (int n = 0; n < 8; n++) {
      acc[n][0] = fmaf(xs[n], wv.x, acc[n][0]);
      acc[n][1] = fmaf(xs[n], wv.y, acc[n][1]);
      acc[n][2] = fmaf(xs[n], wv.z, acc[n][2]);
      acc[n][3] = fmaf(xs[n], wv.w, acc[n][3]);
    }
  }
#pragma unroll
  for (int n = 0; n < 8; n++)
#pragma unroll
    for (int j = 0; j < 4; j++) red[ks][c4][n * 4 + j] = acc[n][j];
  __syncthreads();
  for (int o = tid; o < 2048; o += 256) {
    int col = o & 255, n = o >> 8;
    int cc = col >> 2, j = col & 3;
    float s = red[0][cc][n * 4 + j] + red[1][cc][n * 4 + j] +
              red[2][cc][n * 4 + j] + red[3][cc][n * 4 + j];
    part[(size_t)c * 2048 + n * 256 + col] = s;
  }
}

// ---------------- reduce1 stage A/B ----------------
__global__ __launch_bounds__(256) void k_reduce1a(const float* __restrict__ part,
    float* __restrict__ partr) {
  int bx = blockIdx.x;
  int t = blockIdx.y * 256 + threadIdx.x;
  int cbeg = bx * 61;
  int cend = cbeg + 61;
  if (cend > 963) cend = 963;
  float s = 0.f;
  for (int c = cbeg; c < cend; c++) s += part[(size_t)c * 2048 + t];
  partr[(size_t)bx * 2048 + t] = s;
}

__global__ __launch_bounds__(256) void k_reduce1b(const float* __restrict__ partr,
    const float* __restrict__ bd1, float* __restrict__ d1t) {
  int t = blockIdx.x * 256 + threadIdx.x;
  if (t >= 2048) return;
  float s = 0.f;
#pragma unroll
  for (int b = 0; b < 16; b++) s += partr[(size_t)b * 2048 + t];
  int n = t >> 8, j = t & 255;
  float v = s + bd1[j];
  d1t[j * 8 + n] = fmaxf(v, 0.f);
}

// ---------------- dense2 full-K fused: (8,256) @ (256,38400) + bias ----------------
__global__ __launch_bounds__(256) void k_dense2f(const float* __restrict__ d1t,
    const float* __restrict__ wd2, const float* __restrict__ bd2, float* __restrict__ d2) {
  __shared__ float red[4][64][32];
  int jb = blockIdx.x;
  int tid = threadIdx.x;
  int c4 = tid & 63;
  int ks = tid >> 6;
  int j0 = jb * 256 + c4 * 4;
  float acc[8][4];
#pragma unroll
  for (int n = 0; n < 8; n++)
#pragma unroll
    for (int j = 0; j < 4; j++) acc[n][j] = 0.f;
#pragma unroll 1
  for (int kk = 0; kk < 64; kk++) {
    int row = ks * 64 + kk;
    float4 wv = *(const float4*)(wd2 + (size_t)row * 38400 + j0);
    float4 xa = *(const float4*)(d1t + row * 8);
    float4 xb = *(const float4*)(d1t + row * 8 + 4);
    float xs[8] = {xa.x, xa.y, xa.z, xa.w, xb.x, xb.y, xb.z, xb.w};
#pragma unroll
    for (int n = 0; n < 8; n++) {
      acc[n][0] = fmaf(xs[n], wv.x, acc[n][0]);
      acc[n][1] = fmaf(xs[n], wv.y, acc[n][1]);
      acc[n][2] = fmaf(xs[n], wv.z, acc[n][2]);
      acc[n][3] = fmaf(xs[n], wv.w, acc[n][3]);
    }
  }
#pragma unroll
  for (int n = 0; n < 8; n++)
#pragma unroll
    for (int j = 0; j < 4; j++) red[ks][c4][n * 4 + j] = acc[n][j];
  __syncthreads();
  for (int o = tid; o < 2048; o += 256) {
    int col = o & 255, n = o >> 8;
    int cc = col >> 2, j = col & 3;
    float s = red[0][cc][n * 4 + j] + red[1][cc][n * 4 + j] +
              red[2][cc][n * 4 + j] + red[3][cc][n * 4 + j] + bd2[jb * 256 + col];
    d2[(size_t)n * 38400 + jb * 256 + col] = s;
  }
}

// ---------------- transform + keep-zero fused ----------------
__global__ __launch_bounds__(256) void k_transform(const float* __restrict__ d2,
    float* __restrict__ pred, float* __restrict__ boxd, float* __restrict__ keep_out) {
  int t = blockIdx.x * 256 + threadIdx.x;
  if (t < 115200) keep_out[t] = 0.f;
  if (t >= 19200) return;
  int cell = t % 2400;
  int n = t / 2400;
  float gx = (float)(cell % 60), gy = (float)(cell / 60);
  const float* p = d2 + (size_t)t * 16;
  float o[16];
  o[0] = (sigmoidf_(p[0]) + gx) * 4.0f;
  o[1] = (sigmoidf_(p[1]) + gy) * 4.0f;
  o[2] = expf(p[2]) * 60.0f * 4.0f;
  o[3] = expf(p[3]) * 30.0f * 4.0f;
  o[4] = sigmoidf_(p[4]);
  o[5] = sigmoidf_(p[5]);
  o[6] = sigmoidf_(p[6]);
  o[7] = sigmoidf_(p[7]);
  o[8] = (p[8] + gx) * 4.0f;
  o[9] = (p[9] + gy) * 4.0f;
  o[10] = expf(p[10]) * 20.0f * 4.0f;
  o[11] = expf(p[11]) * 40.0f * 4.0f;
  o[12] = p[12];
  o[13] = sigmoidf_(p[13]);
  o[14] = sigmoidf_(p[14]);
  o[15] = sigmoidf_(p[15]);
  float* op = pred + (size_t)t * 16;
#pragma unroll
  for (int q = 0; q < 16; q++) op[q] = o[q];
#pragma unroll
  for (int h = 0; h < 2; h++) {
    int b = n * 4800 + h * 2400 + cell;
    float X = o[h * 8 + 0], Y = o[h * 8 + 1], W = o[h * 8 + 2], H = o[h * 8 + 3];
    float conf = o[h * 8 + 4];
    float c0 = o[h * 8 + 5], c1 = o[h * 8 + 6], c2 = o[h * 8 + 7];
    int cls = 0; float best = c0;
    if (c1 > best) { best = c1; cls = 1; }
    if (c2 > best) { best = c2; cls = 2; }
    float x1 = X - W / 2.0f, y1 = Y - H / 2.0f;
    float x2 = X + W / 2.0f, y2 = Y + H / 2.0f;
    float area = (x2 - x1 + 1.0f) * (y2 - y1 + 1.0f);
    float* bp2 = boxd + (size_t)b * 8;
    bp2[0] = x1; bp2[1] = y1; bp2[2] = x2; bp2[3] = y2;
    bp2[4] = area; bp2[5] = conf;
    ((int*)bp2)[6] = cls; bp2[7] = 0.f;
  }
}

// ---------------- NMS: one block per (image, class), LDS-resident ----------------
// compact -> bitonic sort -> (V<=1024) latency-hidden bit-matrix build (shfl
// broadcast, no LDS in inner loop) + wave-0 register-avail linear scan with
// software-pipelined row loads.  (V>1024 fallback = r6-validated greedy.)
__global__ __launch_bounds__(256) void k_nms(const float* __restrict__ boxd,
    float* __restrict__ keep_out) {
  __shared__ unsigned long long buf64[18960];  // 151,680 B, manually partitioned
  __shared__ int scnt;
  int bid = blockIdx.x;  // 0..23
  int n = bid / 3, c = bid - n * 3;
  int tid = threadIdx.x;
  int l = tid & 63, wv = tid >> 6;
  const float* bd = boxd + (size_t)n * 4800 * 8;
  unsigned long long* key = buf64;  // [0, 65536 B)
  if (tid == 0) scnt = 0;
  __syncthreads();

  // ---- compact ----
  for (int p = tid; p < 4800; p += 256) {
    const float* bp = bd + (size_t)p * 8;
    float conf = bp[5];
    int cls = ((const int*)bp)[6];
    if (conf > 0.5f && cls == c) {
      int slot = atomicAdd(&scnt, 1);
      unsigned u = __float_as_uint(conf);
      unsigned asc = (u & 0x80000000u) ? ~u : (u | 0x80000000u);
      key[slot] = (((unsigned long long)(~asc)) << 32) | (unsigned)p;
    }
  }
  __syncthreads();
  int V = scnt;
  if (V == 0) return;
  int Vp2 = 1;
  while (Vp2 < V) Vp2 <<= 1;
  for (int s = V + tid; s < Vp2; s += 256) key[s] = ~0ull;

  // ---- bitonic sort ascending -> score desc, idx asc ----
  for (int k = 2; k <= Vp2; k <<= 1) {
    for (int j = k >> 1; j > 0; j >>= 1) {
      __syncthreads();
      int jm = j - 1;
      for (int t2 = tid; t2 < (Vp2 >> 1); t2 += 256) {
        int i = ((t2 & ~jm) << 1) | (t2 & jm);
        int q = i | j;
        bool up = ((i & k) == 0);
        unsigned long long a = key[i], b2 = key[q];
        if ((a > b2) == up) { key[i] = b2; key[q] = a; }
      }
    }
  }
  __syncthreads();
  float* ko = keep_out + (size_t)bid * 4800;

  if (V <= 1024) {
    // ======== fast path: bit-matrix (shfl build) + register-avail scan ========
    int W = (V + 63) >> 6;                     // <= 16 words/row
    unsigned long long* mat = buf64;           // [0, 131072 B), overwrites key
    float4* sb = (float4*)(buf64 + 16384);     // byte 131072, 1024 * 16 B
    int* sidx = (int*)(buf64 + 18432);         // byte 147456, 1024 * 4 B
    for (int s = tid; s < V; s += 256) {
      unsigned long long kk = key[s];
      unsigned p = (unsigned)(kk & 0xFFFFFFFFull);
      const float* bp = bd + (size_t)p * 8;
      sb[s] = make_float4(bp[0], bp[1], bp[2], bp[3]);
      sidx[s] = (int)p;
    }
    __syncthreads();  // key consumed; mat may overwrite

    // build: wave wv owns word-columns w = wv, wv+4, ...
    for (int w = wv; w < W; w += 4) {
      int col = (w << 6) + l;
      float4 bj = sb[col < V ? col : (V - 1)];
      float aj = (bj.z - bj.x + 1.0f) * (bj.w - bj.y + 1.0f);
      int rl = (w + 1) << 6;
      if (rl > V) rl = V;
      for (int i0 = 0; i0 < rl; i0 += 64) {
        int src = i0 + l;
        float4 bv = sb[src < V ? src : (V - 1)];  // 64 rows staged in regs
        int kmax = rl - i0;
        if (kmax > 64) kmax = 64;
        for (int k = 0; k < kmax; k++) {
          float bix = __shfl(bv.x, k, 64);
          float biy = __shfl(bv.y, k, 64);
          float biz = __shfl(bv.z, k, 64);
          float biw = __shfl(bv.w, k, 64);
          float iw = fminf(biz, bj.z) - fmaxf(bix, bj.x) + 1.0f;
          float ih = fminf(biw, bj.w) - fmaxf(biy, bj.y) + 1.0f;
          iw = fmaxf(iw, 0.f);
          ih = fmaxf(ih, 0.f);
          float inter = iw * ih;
          float ai = (biz - bix + 1.0f) * (biw - biy + 1.0f);
          float iou = inter / (ai + aj - inter);
          int i = i0 + k;
          bool pr = (col > i) && (col < V) && (iou >= 0.4f);
          unsigned long long word = __ballot(pr);
          if (l == 0) mat[(size_t)i * W + w] = word;
        }
      }
    }
    __syncthreads();
    if (wv != 0) return;

    // wave-0 scan: lane l holds avail word l in a register
    unsigned long long av = 0ull;
    if (l < W) {
      int rem = V - (l << 6);
      av = (rem >= 64) ? ~0ull : (rem <= 0 ? 0ull : ((1ull << rem) - 1ull));
    }
    for (int i0 = 0; i0 < V; i0 += 8) {
      unsigned long long m[8];
#pragma unroll
      for (int k = 0; k < 8; k++)
        m[k] = (l < W && (i0 + k) < V) ? mat[(size_t)(i0 + k) * W + l] : 0ull;
      int sv = (l < 8 && (i0 + l) < V) ? sidx[i0 + l] : 0;
#pragma unroll
      for (int k = 0; k < 8; k++) {
        int i = i0 + k;
        if (i < V) {
          int wi = i >> 6;
          unsigned long long aw = __shfl(av, wi, 64);
          if ((aw >> (i & 63)) & 1ull) {  // uniform branch
            int sid = __shfl(sv, k, 64);
            if (l == 0) ko[sid] = 1.0f;
            if (l >= wi) av &= ~m[k];
          }
        }
      }
    }
    return;
  }

  // ======== slow path (V > 1024): r6-validated greedy ========
  {
    float4* sb = (float4*)(buf64 + 8192);        // byte 65536, 4800 * 16 B
    unsigned long long* avail = buf64 + 17792;   // byte 142336, 75 words
    for (int s = tid; s < V; s += 256) {
      unsigned p = (unsigned)(key[s] & 0xFFFFFFFFull);
      const float* bp = bd + (size_t)p * 8;
      sb[s] = make_float4(bp[0], bp[1], bp[2], bp[3]);
    }
    for (int w = tid; w < 75; w += 256) {
      int rem = V - (w << 6);
      avail[w] = (rem >= 64) ? ~0ull : (rem <= 0 ? 0ull : ((1ull << rem) - 1ull));
    }
    __syncthreads();
    if (tid >= 64) return;
    int wlast = (V - 1) >> 6;
    for (;;) {
      int cand = 0x7FFFFFFF;
      unsigned long long a0 = avail[l];
      if (a0) cand = (l << 6) + __ffsll((long long)a0) - 1;
      if (l < 11) {
        unsigned long long a1 = avail[64 + l];
        if (a1) {
          int c2 = ((64 + l) << 6) + __ffsll((long long)a1) - 1;
          if (c2 < cand) cand = c2;
        }
      }
#pragma unroll
      for (int off = 32; off > 0; off >>= 1) {
        int o = __shfl_xor(cand, off, 64);
        if (o < cand) cand = o;
      }
      if (cand == 0x7FFFFFFF) break;
      int i = cand;
      int tw = i >> 6;
      if (l == 0) {
        ko[(unsigned)(key[i] & 0xFFFFFFFFull)] = 1.0f;
        avail[tw] &= ~(1ull << (i & 63));
      }
      float4 bi = sb[i];
      float ai = (bi.z - bi.x + 1.0f) * (bi.w - bi.y + 1.0f);
      for (int w = tw; w <= wlast; w++) {
        unsigned long long aw = avail[w];
        if (!aw) continue;
        int col = (w << 6) + l;
        float4 bj = sb[col];
        float iw = fminf(bi.z, bj.z) - fmaxf(bi.x, bj.x) + 1.0f;
        float ih = fminf(bi.w, bj.w) - fmaxf(bi.y, bj.y) + 1.0f;
        iw = fmaxf(iw, 0.f);
        ih = fmaxf(ih, 0.f);
        float inter = iw * ih;
        float aj = (bj.z - bj.x + 1.0f) * (bj.w - bj.y + 1.0f);
        float iou = inter / (ai + aj - inter);
        bool pr = (col > i) && (col < V) && (iou >= 0.4f);
        unsigned long long word = __ballot(pr);
        if (word && l == 0) avail[w] = aw & ~word;
      }
    }
  }
}

extern "C" void kernel_launch(void* const* d_in, const int* in_sizes, int n_in,
                              void* d_out, int out_size, void* d_ws, size_t ws_size,
                              hipStream_t stream) {
  const float* img = (const float*)d_in[0];
  const float* w1 = (const float*)d_in[1];
  const float* b1 = (const float*)d_in[2];
  const float* w2 = (const float*)d_in[3];
  const float* b2 = (const float*)d_in[4];
  const float* w3 = (const float*)d_in[5];
  const float* b3 = (const float*)d_in[6];
  const float* wd1 = (const float*)d_in[7];
  const float* bd1 = (const float*)d_in[8];
  const float* wd2 = (const float*)d_in[9];
  const float* bd2 = (const float*)d_in[10];

  float* ws = (float*)d_ws;
  float* a3 = ws + 0;                 // 1,971,200
  float* pd1 = ws + 3942400;          // 963*2048 = 1,972,224
  float* partr = ws + 5914624;        // 16*2048
  float* d1t = ws + 5947392;          // 2048
  float* d2 = ws + 5949440;           // 307,200
  float* boxd = ws + 6256640;         // 307,200
  float* p1 = ws + 9324800;           // 2,306,304 pooled conv1
  float* p2 = ws + 16047104;          // 1,079,808 pooled conv2

  float* pred = (float*)d_out;
  float* keep = pred + 307200;

  k_conv1p<<<dim3(8, 10, 8), 256, 0, stream>>>(img, w1, b1, p1);
  k_conv2p<<<dim3(8, 10, 8), 128, 0, stream>>>(p1, w2, b2, p2);
  k_conv3<<<dim3(4, 5, 16), 256, 0, stream>>>(p2, w3, b3, a3);
  k_dense1<<<963, 256, 0, stream>>>(a3, wd1, pd1);
  k_reduce1a<<<dim3(16, 8), 256, 0, stream>>>(pd1, partr);
  k_reduce1b<<<8, 256, 0, stream>>>(partr, bd1, d1t);
  k_dense2f<<<150, 256, 0, stream>>>(d1t, wd2, bd2, d2);
  k_transform<<<450, 256, 0, stream>>>(d2, pred, boxd, keep);
  k_nms<<<24, 256, 0, stream>>>(boxd, keep);
}

// Round 9
// 595.758 us; speedup vs baseline: 1.0527x; 1.0266x over previous
//
#include <hip/hip_runtime.h>
#include <stdint.h>

// Pipeline:
// img (8,160,240,3) -> conv1 6x6 (+fused 2x2 pool) -> (8,77,117,32)
// -> conv2 3x3 (+fused 2x2 pool) -> (8,37,57,64)
// -> conv3 3x3 -> (8,35,55,128) -> flatten 246400 -> dense 256 -> dense 38400
// -> transform -> pred (8,40,60,16); NMS (sort -> grid-parallel IoU matrix ->
// linear scan) -> keep (8,3,4800)

static __device__ __forceinline__ float sigmoidf_(float x) {
  return 1.0f / (1.0f + expf(-x));
}

// ---------------- conv1 6x6x3->32 + fused 2x2 maxpool ----------------
__global__ __launch_bounds__(256) void k_conv1p(const float* __restrict__ in,
    const float* __restrict__ w, const float* __restrict__ bias, float* __restrict__ out) {
  __shared__ float s_in[21 * 37 * 3];    // [y][x][c]
  __shared__ float s_w[6 * 6 * 3 * 32];  // [ky][kx][c][o]
  int tx = blockIdx.x, ty = blockIdx.y, n = blockIdx.z;
  int tid = threadIdx.x;
  int iy0 = ty * 16, ix0 = tx * 32;
  for (int idx = tid; idx < 3456; idx += 256) s_w[idx] = w[idx];
  for (int idx = tid; idx < 21 * 37 * 3; idx += 256) {
    int c = idx % 3;
    int rem = idx / 3;
    int x = rem % 37, y = rem / 37;
    int gy = iy0 + y, gx = ix0 + x;
    float v = 0.f;
    if (gy < 160 && gx < 240) v = in[((size_t)(n * 160 + gy) * 240 + gx) * 3 + c];
    s_in[idx] = v;
  }
  __syncthreads();

  int cg = tid >> 6;
  int l = tid & 63;
  int py = l >> 2;
  int px0 = (l & 3) * 8;

  float acc[8][8];
  float bj[8];
#pragma unroll
  for (int j = 0; j < 8; j++) bj[j] = bias[cg * 8 + j];
#pragma unroll
  for (int k = 0; k < 8; k++)
#pragma unroll
    for (int j = 0; j < 8; j++) acc[k][j] = bj[j];

#pragma unroll 1
  for (int ky = 0; ky < 6; ky++) {
#pragma unroll 1
    for (int kx = 0; kx < 6; kx++) {
#pragma unroll 1
      for (int c = 0; c < 3; c++) {
        const float* ib = s_in + ((py + ky) * 37 + px0 + kx) * 3 + c;
        float iv[8];
#pragma unroll
        for (int k = 0; k < 8; k++) iv[k] = ib[k * 3];
        const float* wb = s_w + ((ky * 6 + kx) * 3 + c) * 32 + cg * 8;
        float wv[8];
#pragma unroll
        for (int j = 0; j < 8; j++) wv[j] = wb[j];
#pragma unroll
        for (int k = 0; k < 8; k++)
#pragma unroll
          for (int j = 0; j < 8; j++) acc[k][j] = fmaf(iv[k], wv[j], acc[k][j]);
      }
    }
  }
  float pm[4][8];
#pragma unroll
  for (int kk = 0; kk < 4; kk++)
#pragma unroll
    for (int j = 0; j < 8; j++) pm[kk][j] = fmaxf(acc[2 * kk][j], acc[2 * kk + 1][j]);
#pragma unroll
  for (int kk = 0; kk < 4; kk++)
#pragma unroll
    for (int j = 0; j < 8; j++) {
      float o = __shfl_down(pm[kk][j], 4);
      pm[kk][j] = fmaxf(pm[kk][j], o);
    }
  if (!(py & 1)) {
    int pyp = ty * 8 + (py >> 1);
    if (pyp < 77) {
#pragma unroll
      for (int kk = 0; kk < 4; kk++) {
        int pxp = tx * 16 + (l & 3) * 4 + kk;
        if (pxp < 117) {
          float* op = out + ((size_t)(n * 77 + pyp) * 117 + pxp) * 32 + cg * 8;
          float4 v0, v1;
          v0.x = fmaxf(pm[kk][0], 0.f); v0.y = fmaxf(pm[kk][1], 0.f);
          v0.z = fmaxf(pm[kk][2], 0.f); v0.w = fmaxf(pm[kk][3], 0.f);
          v1.x = fmaxf(pm[kk][4], 0.f); v1.y = fmaxf(pm[kk][5], 0.f);
          v1.z = fmaxf(pm[kk][6], 0.f); v1.w = fmaxf(pm[kk][7], 0.f);
          ((float4*)op)[0] = v0;
          ((float4*)op)[1] = v1;
        }
      }
    }
  }
}

// ---------------- conv2 3x3x32->64 + fused 2x2 maxpool ----------------
__global__ __launch_bounds__(128) void k_conv2p(const float* __restrict__ in,
    const float* __restrict__ w, const float* __restrict__ bias, float* __restrict__ out) {
  __shared__ float s_in[32 * 10 * 18];  // [c][y][x]
  int tx = blockIdx.x, ty = blockIdx.y, n = blockIdx.z;
  int tid = threadIdx.x;
  int iy0 = ty * 8, ix0 = tx * 16;
  for (int idx = tid; idx < 10 * 18 * 32; idx += 128) {
    int c = idx & 31;
    int rem = idx >> 5;
    int x = rem % 18, y = rem / 18;
    int gy = iy0 + y, gx = ix0 + x;
    float v = 0.f;
    if (gy < 77 && gx < 117) v = in[((size_t)(n * 77 + gy) * 117 + gx) * 32 + c];
    s_in[c * 180 + y * 18 + x] = v;
  }
  __syncthreads();

  int cg = tid >> 4;
  int pg = tid & 15;
  int py = pg >> 1;
  int px0 = (pg & 1) * 8;

  float acc[8][8];
  float bj[8];
#pragma unroll
  for (int j = 0; j < 8; j++) bj[j] = bias[cg * 8 + j];
#pragma unroll
  for (int k = 0; k < 8; k++)
#pragma unroll
    for (int j = 0; j < 8; j++) acc[k][j] = bj[j];

#pragma unroll 1
  for (int ky = 0; ky < 3; ky++) {
#pragma unroll 1
    for (int kx = 0; kx < 3; kx++) {
      const float* wbase = w + (size_t)((ky * 3 + kx) * 32) * 64 + cg * 8;
      const float* ibase = s_in + (py + ky) * 18 + px0 + kx;
#pragma unroll 4
      for (int c = 0; c < 32; c++) {
        float4 wa = *(const float4*)(wbase + (size_t)c * 64);
        float4 wb = *(const float4*)(wbase + (size_t)c * 64 + 4);
        const float* ib = ibase + c * 180;
        float iv[8];
#pragma unroll
        for (int k = 0; k < 8; k++) iv[k] = ib[k];
#pragma unroll
        for (int k = 0; k < 8; k++) {
          acc[k][0] = fmaf(iv[k], wa.x, acc[k][0]);
          acc[k][1] = fmaf(iv[k], wa.y, acc[k][1]);
          acc[k][2] = fmaf(iv[k], wa.z, acc[k][2]);
          acc[k][3] = fmaf(iv[k], wa.w, acc[k][3]);
          acc[k][4] = fmaf(iv[k], wb.x, acc[k][4]);
          acc[k][5] = fmaf(iv[k], wb.y, acc[k][5]);
          acc[k][6] = fmaf(iv[k], wb.z, acc[k][6]);
          acc[k][7] = fmaf(iv[k], wb.w, acc[k][7]);
        }
      }
    }
  }
  float pm[4][8];
#pragma unroll
  for (int kk = 0; kk < 4; kk++)
#pragma unroll
    for (int j = 0; j < 8; j++) pm[kk][j] = fmaxf(acc[2 * kk][j], acc[2 * kk + 1][j]);
#pragma unroll
  for (int kk = 0; kk < 4; kk++)
#pragma unroll
    for (int j = 0; j < 8; j++) {
      float o = __shfl_down(pm[kk][j], 2);
      pm[kk][j] = fmaxf(pm[kk][j], o);
    }
  if (!(pg & 2)) {
    int pyp = ty * 4 + (py >> 1);
    if (pyp < 37) {
#pragma unroll
      for (int kk = 0; kk < 4; kk++) {
        int pxp = tx * 8 + (pg & 1) * 4 + kk;
        if (pxp < 57) {
          float* op = out + ((size_t)(n * 37 + pyp) * 57 + pxp) * 64 + cg * 8;
          float4 v0, v1;
          v0.x = fmaxf(pm[kk][0], 0.f); v0.y = fmaxf(pm[kk][1], 0.f);
          v0.z = fmaxf(pm[kk][2], 0.f); v0.w = fmaxf(pm[kk][3], 0.f);
          v1.x = fmaxf(pm[kk][4], 0.f); v1.y = fmaxf(pm[kk][5], 0.f);
          v1.z = fmaxf(pm[kk][6], 0.f); v1.w = fmaxf(pm[kk][7], 0.f);
          ((float4*)op)[0] = v0;
          ((float4*)op)[1] = v1;
        }
      }
    }
  }
}

// ---------------- conv3: 3x3x64 -> 128, channel-split x2 ----------------
__global__ __launch_bounds__(256) void k_conv3(const float* __restrict__ in,
    const float* __restrict__ w, const float* __restrict__ bias, float* __restrict__ out) {
  __shared__ float s_in[64 * 10 * 18];  // [c][y][x]
  int tx = blockIdx.x, ty = blockIdx.y, z = blockIdx.z;
  int n = z >> 1, h = z & 1;
  int tid = threadIdx.x;
  int iy0 = ty * 8, ix0 = tx * 16;
  for (int idx = tid; idx < 10 * 18 * 64; idx += 256) {
    int c = idx & 63;
    int rem = idx >> 6;
    int x = rem % 18, y = rem / 18;
    int gy = iy0 + y, gx = ix0 + x;
    float v = 0.f;
    if (gy < 37 && gx < 57) v = in[((size_t)(n * 37 + gy) * 57 + gx) * 64 + c];
    s_in[c * 180 + y * 18 + x] = v;
  }
  __syncthreads();

  int cg = tid >> 4;
  int pg = tid & 15;
  int py = pg >> 1;
  int px0 = (pg & 1) * 8;
  int ob = h * 64 + cg * 4;

  float acc[8][4];
  float bj[4];
#pragma unroll
  for (int j = 0; j < 4; j++) bj[j] = bias[ob + j];
#pragma unroll
  for (int k = 0; k < 8; k++)
#pragma unroll
    for (int j = 0; j < 4; j++) acc[k][j] = bj[j];

#pragma unroll 1
  for (int ky = 0; ky < 3; ky++) {
#pragma unroll 1
    for (int kx = 0; kx < 3; kx++) {
      const float* wbase = w + (size_t)((ky * 3 + kx) * 64) * 128 + ob;
      const float* ibase = s_in + (py + ky) * 18 + px0 + kx;
#pragma unroll 4
      for (int c = 0; c < 64; c++) {
        float4 wa = *(const float4*)(wbase + (size_t)c * 128);
        const float* ib = ibase + c * 180;
        float iv[8];
#pragma unroll
        for (int k = 0; k < 8; k++) iv[k] = ib[k];
#pragma unroll
        for (int k = 0; k < 8; k++) {
          acc[k][0] = fmaf(iv[k], wa.x, acc[k][0]);
          acc[k][1] = fmaf(iv[k], wa.y, acc[k][1]);
          acc[k][2] = fmaf(iv[k], wa.z, acc[k][2]);
          acc[k][3] = fmaf(iv[k], wa.w, acc[k][3]);
        }
      }
    }
  }
  int oy = iy0 + py;
  if (oy < 35) {
#pragma unroll
    for (int k = 0; k < 8; k++) {
      int ox = ix0 + px0 + k;
      if (ox < 55) {
        float* op = out + ((size_t)(n * 35 + oy) * 55 + ox) * 128 + ob;
        float4 v0;
        v0.x = fmaxf(acc[k][0], 0.f); v0.y = fmaxf(acc[k][1], 0.f);
        v0.z = fmaxf(acc[k][2], 0.f); v0.w = fmaxf(acc[k][3], 0.f);
        ((float4*)op)[0] = v0;
      }
    }
  }
}

// ---------------- dense1: (8,246400) @ (246400,256), split-K, x staged in LDS ----------------
__global__ __launch_bounds__(256) void k_dense1(const float* __restrict__ a3,
    const float* __restrict__ wd1, float* __restrict__ part) {
  __shared__ float red[4][64][32];
  __shared__ float s_x[256][8];
  int c = blockIdx.x;
  int tid = threadIdx.x;
  int c4 = tid & 63;
  int ks = tid >> 6;
  int k0 = c * 256;
  int kn = 246400 - k0;
  if (kn > 256) kn = 256;
  for (int idx = tid; idx < 2048; idx += 256) {
    int nn = idx >> 8, r = idx & 255;
    int rr = k0 + r;
    if (rr > 246399) rr = 246399;
    s_x[r][nn] = a3[(size_t)nn * 246400 + rr];
  }
  __syncthreads();
  float acc[8][4];
#pragma unroll
  for (int n = 0; n < 8; n++)
#pragma unroll
    for (int j = 0; j < 4; j++) acc[n][j] = 0.f;
  int kbeg = ks * 64;
  int kend = kbeg + 64;
  if (kend > kn) kend = kn;
#pragma unroll 1
  for (int kk = kbeg; kk < kend; kk++) {
    float4 wv = *(const float4*)(wd1 + (size_t)(k0 + kk) * 256 + c4 * 4);
    float4 xa = *(const float4*)&s_x[kk][0];
    float4 xb = *(const float4*)&s_x[kk][4];
    float xs[8] = {xa.x, xa.y, xa.z, xa.w, xb.x, xb.y, xb.z, xb.w};
#pragma unroll
    for (int n = 0; n < 8; n++) {
      acc[n][0] = fmaf(xs[n], wv.x, acc[n][0]);
      acc[n][1] = fmaf(xs[n], wv.y, acc[n][1]);
      acc[n][2] = fmaf(xs[n], wv.z, acc[n][2]);
      acc[n][3] = fmaf(xs[n], wv.w, acc[n][3]);
    }
  }
#pragma unroll
  for (int n = 0; n < 8; n++)
#pragma unroll
    for (int j = 0; j < 4; j++) red[ks][c4][n * 4 + j] = acc[n][j];
  __syncthreads();
  for (int o = tid; o < 2048; o += 256) {
    int col = o & 255, n = o >> 8;
    int cc = col >> 2, j = col & 3;
    float s = red[0][cc][n * 4 + j] + red[1][cc][n * 4 + j] +
              red[2][cc][n * 4 + j] + red[3][cc][n * 4 + j];
    part[(size_t)c * 2048 + n * 256 + col] = s;
  }
}

// ---------------- reduce1 stage A/B ----------------
__global__ __launch_bounds__(256) void k_reduce1a(const float* __restrict__ part,
    float* __restrict__ partr) {
  int bx = blockIdx.x;
  int t = blockIdx.y * 256 + threadIdx.x;
  int cbeg = bx * 61;
  int cend = cbeg + 61;
  if (cend > 963) cend = 963;
  float s = 0.f;
  for (int c = cbeg; c < cend; c++) s += part[(size_t)c * 2048 + t];
  partr[(size_t)bx * 2048 + t] = s;
}

__global__ __launch_bounds__(256) void k_reduce1b(const float* __restrict__ partr,
    const float* __restrict__ bd1, float* __restrict__ d1t) {
  int t = blockIdx.x * 256 + threadIdx.x;
  if (t >= 2048) return;
  float s = 0.f;
#pragma unroll
  for (int b = 0; b < 16; b++) s += partr[(size_t)b * 2048 + t];
  int n = t >> 8, j = t & 255;
  float v = s + bd1[j];
  d1t[j * 8 + n] = fmaxf(v, 0.f);
}

// ---------------- dense2 full-K fused: (8,256) @ (256,38400) + bias ----------------
__global__ __launch_bounds__(256) void k_dense2f(const float* __restrict__ d1t,
    const float* __restrict__ wd2, const float* __restrict__ bd2, float* __restrict__ d2) {
  __shared__ float red[4][64][32];
  int jb = blockIdx.x;
  int tid = threadIdx.x;
  int c4 = tid & 63;
  int ks = tid >> 6;
  int j0 = jb * 256 + c4 * 4;
  float acc[8][4];
#pragma unroll
  for (int n = 0; n < 8; n++)
#pragma unroll
    for (int j = 0; j < 4; j++) acc[n][j] = 0.f;
#pragma unroll 1
  for (int kk = 0; kk < 64; kk++) {
    int row = ks * 64 + kk;
    float4 wv = *(const float4*)(wd2 + (size_t)row * 38400 + j0);
    float4 xa = *(const float4*)(d1t + row * 8);
    float4 xb = *(const float4*)(d1t + row * 8 + 4);
    float xs[8] = {xa.x, xa.y, xa.z, xa.w, xb.x, xb.y, xb.z, xb.w};
#pragma unroll
    for (int n = 0; n < 8; n++) {
      acc[n][0] = fmaf(xs[n], wv.x, acc[n][0]);
      acc[n][1] = fmaf(xs[n], wv.y, acc[n][1]);
      acc[n][2] = fmaf(xs[n], wv.z, acc[n][2]);
      acc[n][3] = fmaf(xs[n], wv.w, acc[n][3]);
    }
  }
#pragma unroll
  for (int n = 0; n < 8; n++)
#pragma unroll
    for (int j = 0; j < 4; j++) red[ks][c4][n * 4 + j] = acc[n][j];
  __syncthreads();
  for (int o = tid; o < 2048; o += 256) {
    int col = o & 255, n = o >> 8;
    int cc = col >> 2, j = col & 3;
    float s = red[0][cc][n * 4 + j] + red[1][cc][n * 4 + j] +
              red[2][cc][n * 4 + j] + red[3][cc][n * 4 + j] + bd2[jb * 256 + col];
    d2[(size_t)n * 38400 + jb * 256 + col] = s;
  }
}

// ---------------- transform + keep-zero fused ----------------
__global__ __launch_bounds__(256) void k_transform(const float* __restrict__ d2,
    float* __restrict__ pred, float* __restrict__ boxd, float* __restrict__ keep_out) {
  int t = blockIdx.x * 256 + threadIdx.x;
  if (t < 115200) keep_out[t] = 0.f;
  if (t >= 19200) return;
  int cell = t % 2400;
  int n = t / 2400;
  float gx = (float)(cell % 60), gy = (float)(cell / 60);
  const float* p = d2 + (size_t)t * 16;
  float o[16];
  o[0] = (sigmoidf_(p[0]) + gx) * 4.0f;
  o[1] = (sigmoidf_(p[1]) + gy) * 4.0f;
  o[2] = expf(p[2]) * 60.0f * 4.0f;
  o[3] = expf(p[3]) * 30.0f * 4.0f;
  o[4] = sigmoidf_(p[4]);
  o[5] = sigmoidf_(p[5]);
  o[6] = sigmoidf_(p[6]);
  o[7] = sigmoidf_(p[7]);
  o[8] = (p[8] + gx) * 4.0f;
  o[9] = (p[9] + gy) * 4.0f;
  o[10] = expf(p[10]) * 20.0f * 4.0f;
  o[11] = expf(p[11]) * 40.0f * 4.0f;
  o[12] = p[12];
  o[13] = sigmoidf_(p[13]);
  o[14] = sigmoidf_(p[14]);
  o[15] = sigmoidf_(p[15]);
  float* op = pred + (size_t)t * 16;
#pragma unroll
  for (int q = 0; q < 16; q++) op[q] = o[q];
#pragma unroll
  for (int h = 0; h < 2; h++) {
    int b = n * 4800 + h * 2400 + cell;
    float X = o[h * 8 + 0], Y = o[h * 8 + 1], W = o[h * 8 + 2], H = o[h * 8 + 3];
    float conf = o[h * 8 + 4];
    float c0 = o[h * 8 + 5], c1 = o[h * 8 + 6], c2 = o[h * 8 + 7];
    int cls = 0; float best = c0;
    if (c1 > best) { best = c1; cls = 1; }
    if (c2 > best) { best = c2; cls = 2; }
    float x1 = X - W / 2.0f, y1 = Y - H / 2.0f;
    float x2 = X + W / 2.0f, y2 = Y + H / 2.0f;
    float area = (x2 - x1 + 1.0f) * (y2 - y1 + 1.0f);
    float* bp2 = boxd + (size_t)b * 8;
    bp2[0] = x1; bp2[1] = y1; bp2[2] = x2; bp2[3] = y2;
    bp2[4] = area; bp2[5] = conf;
    ((int*)bp2)[6] = cls; bp2[7] = 0.f;
  }
}

// ---------------- NMS stage 1: compact + sort -> global sorted arrays ----------------
__global__ __launch_bounds__(256) void k_nms_sort(const float* __restrict__ boxd,
    int* __restrict__ cnt, float4* __restrict__ sbf, int* __restrict__ sidx) {
  __shared__ unsigned long long key[8192];
  __shared__ int scnt;
  int bid = blockIdx.x;  // 0..23
  int n = bid / 3, c = bid - n * 3;
  int tid = threadIdx.x;
  const float* bd = boxd + (size_t)n * 4800 * 8;
  if (tid == 0) scnt = 0;
  __syncthreads();

  for (int p = tid; p < 4800; p += 256) {
    const float* bp = bd + (size_t)p * 8;
    float conf = bp[5];
    int cls = ((const int*)bp)[6];
    if (conf > 0.5f && cls == c) {
      int slot = atomicAdd(&scnt, 1);
      unsigned u = __float_as_uint(conf);
      unsigned asc = (u & 0x80000000u) ? ~u : (u | 0x80000000u);
      key[slot] = (((unsigned long long)(~asc)) << 32) | (unsigned)p;
    }
  }
  __syncthreads();
  int V = scnt;
  if (tid == 0) cnt[bid] = V;
  if (V == 0) return;
  int Vp2 = 1;
  while (Vp2 < V) Vp2 <<= 1;
  for (int s = V + tid; s < Vp2; s += 256) key[s] = ~0ull;

  // bitonic sort ascending -> score desc, idx asc (stable argsort(-score))
  for (int k = 2; k <= Vp2; k <<= 1) {
    for (int j = k >> 1; j > 0; j >>= 1) {
      __syncthreads();
      int jm = j - 1;
      for (int t2 = tid; t2 < (Vp2 >> 1); t2 += 256) {
        int i = ((t2 & ~jm) << 1) | (t2 & jm);
        int q = i | j;
        bool up = ((i & k) == 0);
        unsigned long long a = key[i], b2 = key[q];
        if ((a > b2) == up) { key[i] = b2; key[q] = a; }
      }
    }
  }
  __syncthreads();
  float4* sb = sbf + (size_t)bid * 4800;
  int* si = sidx + (size_t)bid * 4800;
  for (int s = tid; s < V; s += 256) {
    unsigned p = (unsigned)(key[s] & 0xFFFFFFFFull);
    const float* bp = bd + (size_t)p * 8;
    sb[s] = make_float4(bp[0], bp[1], bp[2], bp[3]);
    si[s] = (int)p;
  }
}

// ---------------- NMS stage 2: grid-parallel suppression bit-matrix ----------------
// grid (24, 16): block = (nc, word-column w). mat[nc][i][w] row-stride 16 u64.
// Writes ALL words w < W for ALL rows i < V (zeros at/below diagonal).
__global__ __launch_bounds__(256) void k_iou_mat(const int* __restrict__ cnt,
    const float4* __restrict__ sbf, unsigned long long* __restrict__ mat) {
  int nc = blockIdx.x;
  int w = blockIdx.y;
  int V = cnt[nc];
  if (V == 0 || V > 1024) return;
  int W = (V + 63) >> 6;
  if (w >= W) return;
  int tid = threadIdx.x;
  int l = tid & 63, wv = tid >> 6;
  const float4* sb = sbf + (size_t)nc * 4800;
  int col = (w << 6) + l;
  float4 bj = sb[col < V ? col : (V - 1)];
  float aj = (bj.z - bj.x + 1.0f) * (bj.w - bj.y + 1.0f);
  unsigned long long* mrow = mat + (size_t)nc * 1024 * 16 + w;
  for (int i = wv; i < V; i += 4) {
    float4 bi = sb[i];  // wave-uniform, L1/L2-hot
    float iw = fminf(bi.z, bj.z) - fmaxf(bi.x, bj.x) + 1.0f;
    float ih = fminf(bi.w, bj.w) - fmaxf(bi.y, bj.y) + 1.0f;
    iw = fmaxf(iw, 0.f);
    ih = fmaxf(ih, 0.f);
    float inter = iw * ih;
    float ai = (bi.z - bi.x + 1.0f) * (bi.w - bi.y + 1.0f);
    float iou = inter / (ai + aj - inter);
    bool pr = (col > i) && (col < V) && (iou >= 0.4f);
    unsigned long long word = __ballot(pr);
    if (l == 0) mrow[(size_t)i * 16] = word;
  }
}

// ---------------- NMS stage 3: linear greedy scan (wave 0 per block) ----------------
__global__ __launch_bounds__(256) void k_nms_scan(const int* __restrict__ cnt,
    const unsigned long long* __restrict__ mat, const float4* __restrict__ sbf,
    const int* __restrict__ sidx, float* __restrict__ keep_out) {
  __shared__ float4 sbL[4800];            // slow-path staging
  __shared__ unsigned long long avail[75];
  int nc = blockIdx.x;
  int V = cnt[nc];
  if (V == 0) return;
  int tid = threadIdx.x;
  float* ko = keep_out + (size_t)nc * 4800;
  const int* si = sidx + (size_t)nc * 4800;

  if (V <= 1024) {
    if (tid >= 64) return;
    int l = tid;
    int W = (V + 63) >> 6;
    const unsigned long long* mbase = mat + (size_t)nc * 1024 * 16;
    unsigned long long av = 0ull;
    if (l < W) {
      int rem = V - (l << 6);
      av = (rem >= 64) ? ~0ull : ((1ull << rem) - 1ull);
    }
    for (int i0 = 0; i0 < V; i0 += 16) {
      unsigned long long m[16];
#pragma unroll
      for (int k = 0; k < 16; k++)
        m[k] = (l < W && (i0 + k) < V) ? mbase[(size_t)(i0 + k) * 16 + l] : 0ull;
      int sv = (l < 16 && (i0 + l) < V) ? si[i0 + l] : 0;
#pragma unroll
      for (int k = 0; k < 16; k++) {
        int i = i0 + k;
        if (i < V) {
          int wi = i >> 6;
          unsigned long long aw = __shfl(av, wi, 64);
          if ((aw >> (i & 63)) & 1ull) {  // uniform branch
            int sid = __shfl(sv, k, 64);
            if (l == 0) ko[sid] = 1.0f;
            av &= ~m[k];
          }
        }
      }
    }
    return;
  }

  // slow path (V > 1024): r6-validated single-wave greedy, boxes staged in LDS
  {
    const float4* sb = sbf + (size_t)nc * 4800;
    for (int s = tid; s < V; s += 256) sbL[s] = sb[s];
    for (int w = tid; w < 75; w += 256) {
      int rem = V - (w << 6);
      avail[w] = (rem >= 64) ? ~0ull : (rem <= 0 ? 0ull : ((1ull << rem) - 1ull));
    }
    __syncthreads();
    if (tid >= 64) return;
    int l = tid;
    int wlast = (V - 1) >> 6;
    for (;;) {
      int cand = 0x7FFFFFFF;
      unsigned long long a0 = avail[l];
      if (a0) cand = (l << 6) + __ffsll((long long)a0) - 1;
      if (l < 11) {
        unsigned long long a1 = avail[64 + l];
        if (a1) {
          int c2 = ((64 + l) << 6) + __ffsll((long long)a1) - 1;
          if (c2 < cand) cand = c2;
        }
      }
#pragma unroll
      for (int off = 32; off > 0; off >>= 1) {
        int o = __shfl_xor(cand, off, 64);
        if (o < cand) cand = o;
      }
      if (cand == 0x7FFFFFFF) break;
      int i = cand;
      int tw = i >> 6;
      if (l == 0) {
        ko[si[i]] = 1.0f;
        avail[tw] &= ~(1ull << (i & 63));
      }
      float4 bi = sbL[i];
      float ai = (bi.z - bi.x + 1.0f) * (bi.w - bi.y + 1.0f);
      for (int w = tw; w <= wlast; w++) {
        unsigned long long aw = avail[w];
        if (!aw) continue;
        int col = (w << 6) + l;
        float4 bj = sbL[col];
        float iw = fminf(bi.z, bj.z) - fmaxf(bi.x, bj.x) + 1.0f;
        float ih = fminf(bi.w, bj.w) - fmaxf(bi.y, bj.y) + 1.0f;
        iw = fmaxf(iw, 0.f);
        ih = fmaxf(ih, 0.f);
        float inter = iw * ih;
        float aj = (bj.z - bj.x + 1.0f) * (bj.w - bj.y + 1.0f);
        float iou = inter / (ai + aj - inter);
        bool pr = (col > i) && (col < V) && (iou >= 0.4f);
        unsigned long long word = __ballot(pr);
        if (word && l == 0) avail[w] = aw & ~word;
      }
    }
  }
}

extern "C" void kernel_launch(void* const* d_in, const int* in_sizes, int n_in,
                              void* d_out, int out_size, void* d_ws, size_t ws_size,
                              hipStream_t stream) {
  const float* img = (const float*)d_in[0];
  const float* w1 = (const float*)d_in[1];
  const float* b1 = (const float*)d_in[2];
  const float* w2 = (const float*)d_in[3];
  const float* b2 = (const float*)d_in[4];
  const float* w3 = (const float*)d_in[5];
  const float* b3 = (const float*)d_in[6];
  const float* wd1 = (const float*)d_in[7];
  const float* bd1 = (const float*)d_in[8];
  const float* wd2 = (const float*)d_in[9];
  const float* bd2 = (const float*)d_in[10];

  float* ws = (float*)d_ws;
  float* a3 = ws + 0;                 // 1,971,200
  float* pd1 = ws + 3942400;          // 963*2048 = 1,972,224 (dead after reduce1a)
  float* partr = ws + 5914624;        // 16*2048
  float* d1t = ws + 5947392;          // 2048
  float* d2 = ws + 5949440;           // 307,200
  float* boxd = ws + 6256640;         // 307,200
  float4* sbf = (float4*)(ws + 6563840);  // 24*4800 float4 = 460,800 floats
  int* sidx = (int*)(ws + 7024640);   // 115,200
  int* cnt = (int*)(ws + 7139840);    // 24
  float* p1 = ws + 9324800;           // 2,306,304 pooled conv1
  float* p2 = ws + 16047104;          // 1,079,808 pooled conv2
  // mat overlays dead pd1 region: 24*1024*16 u64 = 786,432 floats
  unsigned long long* mat = (unsigned long long*)(ws + 3942400);

  float* pred = (float*)d_out;
  float* keep = pred + 307200;

  k_conv1p<<<dim3(8, 10, 8), 256, 0, stream>>>(img, w1, b1, p1);
  k_conv2p<<<dim3(8, 10, 8), 128, 0, stream>>>(p1, w2, b2, p2);
  k_conv3<<<dim3(4, 5, 16), 256, 0, stream>>>(p2, w3, b3, a3);
  k_dense1<<<963, 256, 0, stream>>>(a3, wd1, pd1);
  k_reduce1a<<<dim3(16, 8), 256, 0, stream>>>(pd1, partr);
  k_reduce1b<<<8, 256, 0, stream>>>(partr, bd1, d1t);
  k_dense2f<<<150, 256, 0, stream>>>(d1t, wd2, bd2, d2);
  k_transform<<<450, 256, 0, stream>>>(d2, pred, boxd, keep);
  k_nms_sort<<<24, 256, 0, stream>>>(boxd, cnt, sbf, sidx);
  k_iou_mat<<<dim3(24, 16), 256, 0, stream>>>(cnt, sbf, mat);
  k_nms_scan<<<24, 256, 0, stream>>>(cnt, mat, sbf, sidx, keep);
}

// Round 10
// 466.987 us; speedup vs baseline: 1.3430x; 1.2757x over previous
//
#include <hip/hip_runtime.h>
#include <stdint.h>

// Pipeline:
// img (8,160,240,3) -> conv1 6x6 (+fused 2x2 pool) -> (8,77,117,32)
// -> conv2 3x3 (+fused 2x2 pool) -> (8,37,57,64)
// -> conv3 3x3 -> (8,35,55,128) -> flatten 246400 -> dense 256 -> dense 38400
// -> transform -> pred (8,40,60,16); NMS (sort -> grid-parallel IoU matrix ->
// register-chain linear scan) -> keep (8,3,4800)

static __device__ __forceinline__ float sigmoidf_(float x) {
  return 1.0f / (1.0f + expf(-x));
}

// ---------------- conv1 6x6x3->32 + fused 2x2 maxpool ----------------
__global__ __launch_bounds__(256) void k_conv1p(const float* __restrict__ in,
    const float* __restrict__ w, const float* __restrict__ bias, float* __restrict__ out) {
  __shared__ float s_in[21 * 37 * 3];    // [y][x][c]
  __shared__ float s_w[6 * 6 * 3 * 32];  // [ky][kx][c][o]
  int tx = blockIdx.x, ty = blockIdx.y, n = blockIdx.z;
  int tid = threadIdx.x;
  int iy0 = ty * 16, ix0 = tx * 32;
  for (int idx = tid; idx < 3456; idx += 256) s_w[idx] = w[idx];
  for (int idx = tid; idx < 21 * 37 * 3; idx += 256) {
    int c = idx % 3;
    int rem = idx / 3;
    int x = rem % 37, y = rem / 37;
    int gy = iy0 + y, gx = ix0 + x;
    float v = 0.f;
    if (gy < 160 && gx < 240) v = in[((size_t)(n * 160 + gy) * 240 + gx) * 3 + c];
    s_in[idx] = v;
  }
  __syncthreads();

  int cg = tid >> 6;
  int l = tid & 63;
  int py = l >> 2;
  int px0 = (l & 3) * 8;

  float acc[8][8];
  float bj[8];
#pragma unroll
  for (int j = 0; j < 8; j++) bj[j] = bias[cg * 8 + j];
#pragma unroll
  for (int k = 0; k < 8; k++)
#pragma unroll
    for (int j = 0; j < 8; j++) acc[k][j] = bj[j];

#pragma unroll 1
  for (int ky = 0; ky < 6; ky++) {
#pragma unroll 1
    for (int kx = 0; kx < 6; kx++) {
#pragma unroll 1
      for (int c = 0; c < 3; c++) {
        const float* ib = s_in + ((py + ky) * 37 + px0 + kx) * 3 + c;
        float iv[8];
#pragma unroll
        for (int k = 0; k < 8; k++) iv[k] = ib[k * 3];
        const float* wb = s_w + ((ky * 6 + kx) * 3 + c) * 32 + cg * 8;
        float wv[8];
#pragma unroll
        for (int j = 0; j < 8; j++) wv[j] = wb[j];
#pragma unroll
        for (int k = 0; k < 8; k++)
#pragma unroll
          for (int j = 0; j < 8; j++) acc[k][j] = fmaf(iv[k], wv[j], acc[k][j]);
      }
    }
  }
  float pm[4][8];
#pragma unroll
  for (int kk = 0; kk < 4; kk++)
#pragma unroll
    for (int j = 0; j < 8; j++) pm[kk][j] = fmaxf(acc[2 * kk][j], acc[2 * kk + 1][j]);
#pragma unroll
  for (int kk = 0; kk < 4; kk++)
#pragma unroll
    for (int j = 0; j < 8; j++) {
      float o = __shfl_down(pm[kk][j], 4);
      pm[kk][j] = fmaxf(pm[kk][j], o);
    }
  if (!(py & 1)) {
    int pyp = ty * 8 + (py >> 1);
    if (pyp < 77) {
#pragma unroll
      for (int kk = 0; kk < 4; kk++) {
        int pxp = tx * 16 + (l & 3) * 4 + kk;
        if (pxp < 117) {
          float* op = out + ((size_t)(n * 77 + pyp) * 117 + pxp) * 32 + cg * 8;
          float4 v0, v1;
          v0.x = fmaxf(pm[kk][0], 0.f); v0.y = fmaxf(pm[kk][1], 0.f);
          v0.z = fmaxf(pm[kk][2], 0.f); v0.w = fmaxf(pm[kk][3], 0.f);
          v1.x = fmaxf(pm[kk][4], 0.f); v1.y = fmaxf(pm[kk][5], 0.f);
          v1.z = fmaxf(pm[kk][6], 0.f); v1.w = fmaxf(pm[kk][7], 0.f);
          ((float4*)op)[0] = v0;
          ((float4*)op)[1] = v1;
        }
      }
    }
  }
}

// ---------------- conv2 3x3x32->64 + fused 2x2 maxpool ----------------
__global__ __launch_bounds__(128) void k_conv2p(const float* __restrict__ in,
    const float* __restrict__ w, const float* __restrict__ bias, float* __restrict__ out) {
  __shared__ float s_in[32 * 10 * 18];  // [c][y][x]
  int tx = blockIdx.x, ty = blockIdx.y, n = blockIdx.z;
  int tid = threadIdx.x;
  int iy0 = ty * 8, ix0 = tx * 16;
  for (int idx = tid; idx < 10 * 18 * 32; idx += 128) {
    int c = idx & 31;
    int rem = idx >> 5;
    int x = rem % 18, y = rem / 18;
    int gy = iy0 + y, gx = ix0 + x;
    float v = 0.f;
    if (gy < 77 && gx < 117) v = in[((size_t)(n * 77 + gy) * 117 + gx) * 32 + c];
    s_in[c * 180 + y * 18 + x] = v;
  }
  __syncthreads();

  int cg = tid >> 4;
  int pg = tid & 15;
  int py = pg >> 1;
  int px0 = (pg & 1) * 8;

  float acc[8][8];
  float bj[8];
#pragma unroll
  for (int j = 0; j < 8; j++) bj[j] = bias[cg * 8 + j];
#pragma unroll
  for (int k = 0; k < 8; k++)
#pragma unroll
    for (int j = 0; j < 8; j++) acc[k][j] = bj[j];

#pragma unroll 1
  for (int ky = 0; ky < 3; ky++) {
#pragma unroll 1
    for (int kx = 0; kx < 3; kx++) {
      const float* wbase = w + (size_t)((ky * 3 + kx) * 32) * 64 + cg * 8;
      const float* ibase = s_in + (py + ky) * 18 + px0 + kx;
#pragma unroll 4
      for (int c = 0; c < 32; c++) {
        float4 wa = *(const float4*)(wbase + (size_t)c * 64);
        float4 wb = *(const float4*)(wbase + (size_t)c * 64 + 4);
        const float* ib = ibase + c * 180;
        float iv[8];
#pragma unroll
        for (int k = 0; k < 8; k++) iv[k] = ib[k];
#pragma unroll
        for (int k = 0; k < 8; k++) {
          acc[k][0] = fmaf(iv[k], wa.x, acc[k][0]);
          acc[k][1] = fmaf(iv[k], wa.y, acc[k][1]);
          acc[k][2] = fmaf(iv[k], wa.z, acc[k][2]);
          acc[k][3] = fmaf(iv[k], wa.w, acc[k][3]);
          acc[k][4] = fmaf(iv[k], wb.x, acc[k][4]);
          acc[k][5] = fmaf(iv[k], wb.y, acc[k][5]);
          acc[k][6] = fmaf(iv[k], wb.z, acc[k][6]);
          acc[k][7] = fmaf(iv[k], wb.w, acc[k][7]);
        }
      }
    }
  }
  float pm[4][8];
#pragma unroll
  for (int kk = 0; kk < 4; kk++)
#pragma unroll
    for (int j = 0; j < 8; j++) pm[kk][j] = fmaxf(acc[2 * kk][j], acc[2 * kk + 1][j]);
#pragma unroll
  for (int kk = 0; kk < 4; kk++)
#pragma unroll
    for (int j = 0; j < 8; j++) {
      float o = __shfl_down(pm[kk][j], 2);
      pm[kk][j] = fmaxf(pm[kk][j], o);
    }
  if (!(pg & 2)) {
    int pyp = ty * 4 + (py >> 1);
    if (pyp < 37) {
#pragma unroll
      for (int kk = 0; kk < 4; kk++) {
        int pxp = tx * 8 + (pg & 1) * 4 + kk;
        if (pxp < 57) {
          float* op = out + ((size_t)(n * 37 + pyp) * 57 + pxp) * 64 + cg * 8;
          float4 v0, v1;
          v0.x = fmaxf(pm[kk][0], 0.f); v0.y = fmaxf(pm[kk][1], 0.f);
          v0.z = fmaxf(pm[kk][2], 0.f); v0.w = fmaxf(pm[kk][3], 0.f);
          v1.x = fmaxf(pm[kk][4], 0.f); v1.y = fmaxf(pm[kk][5], 0.f);
          v1.z = fmaxf(pm[kk][6], 0.f); v1.w = fmaxf(pm[kk][7], 0.f);
          ((float4*)op)[0] = v0;
          ((float4*)op)[1] = v1;
        }
      }
    }
  }
}

// ---------------- conv3: 3x3x64 -> 128, channel-split x2 ----------------
__global__ __launch_bounds__(256) void k_conv3(const float* __restrict__ in,
    const float* __restrict__ w, const float* __restrict__ bias, float* __restrict__ out) {
  __shared__ float s_in[64 * 10 * 18];  // [c][y][x]
  int tx = blockIdx.x, ty = blockIdx.y, z = blockIdx.z;
  int n = z >> 1, h = z & 1;
  int tid = threadIdx.x;
  int iy0 = ty * 8, ix0 = tx * 16;
  for (int idx = tid; idx < 10 * 18 * 64; idx += 256) {
    int c = idx & 63;
    int rem = idx >> 6;
    int x = rem % 18, y = rem / 18;
    int gy = iy0 + y, gx = ix0 + x;
    float v = 0.f;
    if (gy < 37 && gx < 57) v = in[((size_t)(n * 37 + gy) * 57 + gx) * 64 + c];
    s_in[c * 180 + y * 18 + x] = v;
  }
  __syncthreads();

  int cg = tid >> 4;
  int pg = tid & 15;
  int py = pg >> 1;
  int px0 = (pg & 1) * 8;
  int ob = h * 64 + cg * 4;

  float acc[8][4];
  float bj[4];
#pragma unroll
  for (int j = 0; j < 4; j++) bj[j] = bias[ob + j];
#pragma unroll
  for (int k = 0; k < 8; k++)
#pragma unroll
    for (int j = 0; j < 4; j++) acc[k][j] = bj[j];

#pragma unroll 1
  for (int ky = 0; ky < 3; ky++) {
#pragma unroll 1
    for (int kx = 0; kx < 3; kx++) {
      const float* wbase = w + (size_t)((ky * 3 + kx) * 64) * 128 + ob;
      const float* ibase = s_in + (py + ky) * 18 + px0 + kx;
#pragma unroll 4
      for (int c = 0; c < 64; c++) {
        float4 wa = *(const float4*)(wbase + (size_t)c * 128);
        const float* ib = ibase + c * 180;
        float iv[8];
#pragma unroll
        for (int k = 0; k < 8; k++) iv[k] = ib[k];
#pragma unroll
        for (int k = 0; k < 8; k++) {
          acc[k][0] = fmaf(iv[k], wa.x, acc[k][0]);
          acc[k][1] = fmaf(iv[k], wa.y, acc[k][1]);
          acc[k][2] = fmaf(iv[k], wa.z, acc[k][2]);
          acc[k][3] = fmaf(iv[k], wa.w, acc[k][3]);
        }
      }
    }
  }
  int oy = iy0 + py;
  if (oy < 35) {
#pragma unroll
    for (int k = 0; k < 8; k++) {
      int ox = ix0 + px0 + k;
      if (ox < 55) {
        float* op = out + ((size_t)(n * 35 + oy) * 55 + ox) * 128 + ob;
        float4 v0;
        v0.x = fmaxf(acc[k][0], 0.f); v0.y = fmaxf(acc[k][1], 0.f);
        v0.z = fmaxf(acc[k][2], 0.f); v0.w = fmaxf(acc[k][3], 0.f);
        ((float4*)op)[0] = v0;
      }
    }
  }
}

// ---------------- dense1: (8,246400) @ (246400,256), split-K, x staged in LDS ----------------
__global__ __launch_bounds__(256) void k_dense1(const float* __restrict__ a3,
    const float* __restrict__ wd1, float* __restrict__ part) {
  __shared__ float red[4][64][32];
  __shared__ float s_x[256][8];
  int c = blockIdx.x;
  int tid = threadIdx.x;
  int c4 = tid & 63;
  int ks = tid >> 6;
  int k0 = c * 256;
  int kn = 246400 - k0;
  if (kn > 256) kn = 256;
  for (int idx = tid; idx < 2048; idx += 256) {
    int nn = idx >> 8, r = idx & 255;
    int rr = k0 + r;
    if (rr > 246399) rr = 246399;
    s_x[r][nn] = a3[(size_t)nn * 246400 + rr];
  }
  __syncthreads();
  float acc[8][4];
#pragma unroll
  for (int n = 0; n < 8; n++)
#pragma unroll
    for (int j = 0; j < 4; j++) acc[n][j] = 0.f;
  int kbeg = ks * 64;
  int kend = kbeg + 64;
  if (kend > kn) kend = kn;
#pragma unroll 1
  for (int kk = kbeg; kk < kend; kk++) {
    float4 wv = *(const float4*)(wd1 + (size_t)(k0 + kk) * 256 + c4 * 4);
    float4 xa = *(const float4*)&s_x[kk][0];
    float4 xb = *(const float4*)&s_x[kk][4];
    float xs[8] = {xa.x, xa.y, xa.z, xa.w, xb.x, xb.y, xb.z, xb.w};
#pragma unroll
    for (int n = 0; n < 8; n++) {
      acc[n][0] = fmaf(xs[n], wv.x, acc[n][0]);
      acc[n][1] = fmaf(xs[n], wv.y, acc[n][1]);
      acc[n][2] = fmaf(xs[n], wv.z, acc[n][2]);
      acc[n][3] = fmaf(xs[n], wv.w, acc[n][3]);
    }
  }
#pragma unroll
  for (int n = 0; n < 8; n++)
#pragma unroll
    for (int j = 0; j < 4; j++) red[ks][c4][n * 4 + j] = acc[n][j];
  __syncthreads();
  for (int o = tid; o < 2048; o += 256) {
    int col = o & 255, n = o >> 8;
    int cc = col >> 2, j = col & 3;
    float s = red[0][cc][n * 4 + j] + red[1][cc][n * 4 + j] +
              red[2][cc][n * 4 + j] + red[3][cc][n * 4 + j];
    part[(size_t)c * 2048 + n * 256 + col] = s;
  }
}

// ---------------- reduce1 stage A/B ----------------
__global__ __launch_bounds__(256) void k_reduce1a(const float* __restrict__ part,
    float* __restrict__ partr) {
  int bx = blockIdx.x;
  int t = blockIdx.y * 256 + threadIdx.x;
  int cbeg = bx * 61;
  int cend = cbeg + 61;
  if (cend > 963) cend = 963;
  float s = 0.f;
  for (int c = cbeg; c < cend; c++) s += part[(size_t)c * 2048 + t];
  partr[(size_t)bx * 2048 + t] = s;
}

__global__ __launch_bounds__(256) void k_reduce1b(const float* __restrict__ partr,
    const float* __restrict__ bd1, float* __restrict__ d1t) {
  int t = blockIdx.x * 256 + threadIdx.x;
  if (t >= 2048) return;
  float s = 0.f;
#pragma unroll
  for (int b = 0; b < 16; b++) s += partr[(size_t)b * 2048 + t];
  int n = t >> 8, j = t & 255;
  float v = s + bd1[j];
  d1t[j * 8 + n] = fmaxf(v, 0.f);
}

// ---------------- dense2 full-K fused: (8,256) @ (256,38400) + bias ----------------
__global__ __launch_bounds__(256) void k_dense2f(const float* __restrict__ d1t,
    const float* __restrict__ wd2, const float* __restrict__ bd2, float* __restrict__ d2) {
  __shared__ float red[4][64][32];
  int jb = blockIdx.x;
  int tid = threadIdx.x;
  int c4 = tid & 63;
  int ks = tid >> 6;
  int j0 = jb * 256 + c4 * 4;
  float acc[8][4];
#pragma unroll
  for (int n = 0; n < 8; n++)
#pragma unroll
    for (int j = 0; j < 4; j++) acc[n][j] = 0.f;
#pragma unroll 1
  for (int kk = 0; kk < 64; kk++) {
    int row = ks * 64 + kk;
    float4 wv = *(const float4*)(wd2 + (size_t)row * 38400 + j0);
    float4 xa = *(const float4*)(d1t + row * 8);
    float4 xb = *(const float4*)(d1t + row * 8 + 4);
    float xs[8] = {xa.x, xa.y, xa.z, xa.w, xb.x, xb.y, xb.z, xb.w};
#pragma unroll
    for (int n = 0; n < 8; n++) {
      acc[n][0] = fmaf(xs[n], wv.x, acc[n][0]);
      acc[n][1] = fmaf(xs[n], wv.y, acc[n][1]);
      acc[n][2] = fmaf(xs[n], wv.z, acc[n][2]);
      acc[n][3] = fmaf(xs[n], wv.w, acc[n][3]);
    }
  }
#pragma unroll
  for (int n = 0; n < 8; n++)
#pragma unroll
    for (int j = 0; j < 4; j++) red[ks][c4][n * 4 + j] = acc[n][j];
  __syncthreads();
  for (int o = tid; o < 2048; o += 256) {
    int col = o & 255, n = o >> 8;
    int cc = col >> 2, j = col & 3;
    float s = red[0][cc][n * 4 + j] + red[1][cc][n * 4 + j] +
              red[2][cc][n * 4 + j] + red[3][cc][n * 4 + j] + bd2[jb * 256 + col];
    d2[(size_t)n * 38400 + jb * 256 + col] = s;
  }
}

// ---------------- transform + keep-zero fused ----------------
__global__ __launch_bounds__(256) void k_transform(const float* __restrict__ d2,
    float* __restrict__ pred, float* __restrict__ boxd, float* __restrict__ keep_out) {
  int t = blockIdx.x * 256 + threadIdx.x;
  if (t < 115200) keep_out[t] = 0.f;
  if (t >= 19200) return;
  int cell = t % 2400;
  int n = t / 2400;
  float gx = (float)(cell % 60), gy = (float)(cell / 60);
  const float* p = d2 + (size_t)t * 16;
  float o[16];
  o[0] = (sigmoidf_(p[0]) + gx) * 4.0f;
  o[1] = (sigmoidf_(p[1]) + gy) * 4.0f;
  o[2] = expf(p[2]) * 60.0f * 4.0f;
  o[3] = expf(p[3]) * 30.0f * 4.0f;
  o[4] = sigmoidf_(p[4]);
  o[5] = sigmoidf_(p[5]);
  o[6] = sigmoidf_(p[6]);
  o[7] = sigmoidf_(p[7]);
  o[8] = (p[8] + gx) * 4.0f;
  o[9] = (p[9] + gy) * 4.0f;
  o[10] = expf(p[10]) * 20.0f * 4.0f;
  o[11] = expf(p[11]) * 40.0f * 4.0f;
  o[12] = p[12];
  o[13] = sigmoidf_(p[13]);
  o[14] = sigmoidf_(p[14]);
  o[15] = sigmoidf_(p[15]);
  float* op = pred + (size_t)t * 16;
#pragma unroll
  for (int q = 0; q < 16; q++) op[q] = o[q];
#pragma unroll
  for (int h = 0; h < 2; h++) {
    int b = n * 4800 + h * 2400 + cell;
    float X = o[h * 8 + 0], Y = o[h * 8 + 1], W = o[h * 8 + 2], H = o[h * 8 + 3];
    float conf = o[h * 8 + 4];
    float c0 = o[h * 8 + 5], c1 = o[h * 8 + 6], c2 = o[h * 8 + 7];
    int cls = 0; float best = c0;
    if (c1 > best) { best = c1; cls = 1; }
    if (c2 > best) { best = c2; cls = 2; }
    float x1 = X - W / 2.0f, y1 = Y - H / 2.0f;
    float x2 = X + W / 2.0f, y2 = Y + H / 2.0f;
    float area = (x2 - x1 + 1.0f) * (y2 - y1 + 1.0f);
    float* bp2 = boxd + (size_t)b * 8;
    bp2[0] = x1; bp2[1] = y1; bp2[2] = x2; bp2[3] = y2;
    bp2[4] = area; bp2[5] = conf;
    ((int*)bp2)[6] = cls; bp2[7] = 0.f;
  }
}

// ---------------- NMS stage 1: compact + sort -> global sorted arrays ----------------
__global__ __launch_bounds__(256) void k_nms_sort(const float* __restrict__ boxd,
    int* __restrict__ cnt, float4* __restrict__ sbf, int* __restrict__ sidx) {
  __shared__ unsigned long long key[8192];
  __shared__ int scnt;
  int bid = blockIdx.x;  // 0..23
  int n = bid / 3, c = bid - n * 3;
  int tid = threadIdx.x;
  const float* bd = boxd + (size_t)n * 4800 * 8;
  if (tid == 0) scnt = 0;
  __syncthreads();

  for (int p = tid; p < 4800; p += 256) {
    const float* bp = bd + (size_t)p * 8;
    float conf = bp[5];
    int cls = ((const int*)bp)[6];
    if (conf > 0.5f && cls == c) {
      int slot = atomicAdd(&scnt, 1);
      unsigned u = __float_as_uint(conf);
      unsigned asc = (u & 0x80000000u) ? ~u : (u | 0x80000000u);
      key[slot] = (((unsigned long long)(~asc)) << 32) | (unsigned)p;
    }
  }
  __syncthreads();
  int V = scnt;
  if (tid == 0) cnt[bid] = V;
  if (V == 0) return;
  int Vp2 = 1;
  while (Vp2 < V) Vp2 <<= 1;
  for (int s = V + tid; s < Vp2; s += 256) key[s] = ~0ull;

  // bitonic sort ascending -> score desc, idx asc (stable argsort(-score))
  for (int k = 2; k <= Vp2; k <<= 1) {
    for (int j = k >> 1; j > 0; j >>= 1) {
      __syncthreads();
      int jm = j - 1;
      for (int t2 = tid; t2 < (Vp2 >> 1); t2 += 256) {
        int i = ((t2 & ~jm) << 1) | (t2 & jm);
        int q = i | j;
        bool up = ((i & k) == 0);
        unsigned long long a = key[i], b2 = key[q];
        if ((a > b2) == up) { key[i] = b2; key[q] = a; }
      }
    }
  }
  __syncthreads();
  float4* sb = sbf + (size_t)bid * 4800;
  int* si = sidx + (size_t)bid * 4800;
  for (int s = tid; s < V; s += 256) {
    unsigned p = (unsigned)(key[s] & 0xFFFFFFFFull);
    const float* bp = bd + (size_t)p * 8;
    sb[s] = make_float4(bp[0], bp[1], bp[2], bp[3]);
    si[s] = (int)p;
  }
}

// ---------------- NMS stage 2: grid-parallel suppression bit-matrix ----------------
// grid (24, 16): block = (nc, word-column w). mat[nc][i][w] row-stride 16 u64.
__global__ __launch_bounds__(256) void k_iou_mat(const int* __restrict__ cnt,
    const float4* __restrict__ sbf, unsigned long long* __restrict__ mat) {
  int nc = blockIdx.x;
  int w = blockIdx.y;
  int V = cnt[nc];
  if (V == 0 || V > 1024) return;
  int W = (V + 63) >> 6;
  if (w >= W) return;
  int tid = threadIdx.x;
  int l = tid & 63, wv = tid >> 6;
  const float4* sb = sbf + (size_t)nc * 4800;
  int col = (w << 6) + l;
  float4 bj = sb[col < V ? col : (V - 1)];
  float aj = (bj.z - bj.x + 1.0f) * (bj.w - bj.y + 1.0f);
  unsigned long long* mrow = mat + (size_t)nc * 1024 * 16 + w;
  for (int i = wv; i < V; i += 4) {
    float4 bi = sb[i];  // wave-uniform, L1/L2-hot
    float iw = fminf(bi.z, bj.z) - fmaxf(bi.x, bj.x) + 1.0f;
    float ih = fminf(bi.w, bj.w) - fmaxf(bi.y, bj.y) + 1.0f;
    iw = fmaxf(iw, 0.f);
    ih = fmaxf(ih, 0.f);
    float inter = iw * ih;
    float ai = (bi.z - bi.x + 1.0f) * (bi.w - bi.y + 1.0f);
    float iou = inter / (ai + aj - inter);
    bool pr = (col > i) && (col < V) && (iou >= 0.4f);
    unsigned long long word = __ballot(pr);
    if (l == 0) mrow[(size_t)i * 16] = word;
  }
}

// ---------------- NMS stage 3: linear greedy scan, VALU-only serial chain ----------------
__global__ __launch_bounds__(256) void k_nms_scan(const int* __restrict__ cnt,
    const unsigned long long* __restrict__ mat, const float4* __restrict__ sbf,
    const int* __restrict__ sidx, float* __restrict__ keep_out) {
  __shared__ float4 sbL[4800];            // slow-path staging
  __shared__ unsigned long long avail[75];
  int nc = blockIdx.x;
  int V = cnt[nc];
  if (V == 0) return;
  int tid = threadIdx.x;
  float* ko = keep_out + (size_t)nc * 4800;
  const int* si = sidx + (size_t)nc * 4800;

  if (V <= 1024) {
    if (tid >= 64) return;
    int l = tid;
    int W = (V + 63) >> 6;
    const unsigned long long* mbase = mat + (size_t)nc * 1024 * 16;
    bool act = (l < W);
    unsigned long long av = 0ull;  // lane l holds avail word l (distributed)
    if (act) {
      int rem = V - (l << 6);
      av = (rem >= 64) ? ~0ull : ((1ull << rem) - 1ull);
    }
    unsigned long long mA[16], mB[16];
    // prologue: load chunk 0
#pragma unroll
    for (int k = 0; k < 16; k++)
      mA[k] = (act && k < V) ? mbase[(size_t)k * 16 + l] : 0ull;
    for (int i0 = 0; i0 < V; i0 += 16) {
      // prefetch next chunk (independent of the serial chain)
      int nx = i0 + 16;
#pragma unroll
      for (int k = 0; k < 16; k++)
        mB[k] = (act && (nx + k) < V) ? mbase[(size_t)(nx + k) * 16 + l] : 0ull;
      int wi = i0 >> 6;
      // broadcast the local-word slices: independent shfls, off the chain
      unsigned long long mloc[16];
#pragma unroll
      for (int k = 0; k < 16; k++) mloc[k] = __shfl(mA[k], wi, 64);
      unsigned long long cur = __shfl(av, wi, 64);  // once per chunk
      unsigned alive = 0;
#pragma unroll
      for (int k = 0; k < 16; k++) {  // pure-VALU serial chain
        int i = i0 + k;
        if (i < V && ((cur >> (i & 63)) & 1ull)) {
          alive |= 1u << k;
          cur &= ~mloc[k];
        }
      }
      // apply suppressions of alive rows to the distributed availability
#pragma unroll
      for (int k = 0; k < 16; k++)
        if ((alive >> k) & 1u) av &= ~mA[k];
      // keep-writes (parallel, fire-and-forget)
      if (l < 16 && ((alive >> l) & 1u) && (i0 + l) < V) ko[si[i0 + l]] = 1.0f;
#pragma unroll
      for (int k = 0; k < 16; k++) mA[k] = mB[k];
    }
    return;
  }

  // slow path (V > 1024): r6-validated single-wave greedy, boxes staged in LDS
  {
    const float4* sb = sbf + (size_t)nc * 4800;
    for (int s = tid; s < V; s += 256) sbL[s] = sb[s];
    for (int w = tid; w < 75; w += 256) {
      int rem = V - (w << 6);
      avail[w] = (rem >= 64) ? ~0ull : (rem <= 0 ? 0ull : ((1ull << rem) - 1ull));
    }
    __syncthreads();
    if (tid >= 64) return;
    int l = tid;
    int wlast = (V - 1) >> 6;
    for (;;) {
      int cand = 0x7FFFFFFF;
      unsigned long long a0 = avail[l];
      if (a0) cand = (l << 6) + __ffsll((long long)a0) - 1;
      if (l < 11) {
        unsigned long long a1 = avail[64 + l];
        if (a1) {
          int c2 = ((64 + l) << 6) + __ffsll((long long)a1) - 1;
          if (c2 < cand) cand = c2;
        }
      }
#pragma unroll
      for (int off = 32; off > 0; off >>= 1) {
        int o = __shfl_xor(cand, off, 64);
        if (o < cand) cand = o;
      }
      if (cand == 0x7FFFFFFF) break;
      int i = cand;
      int tw = i >> 6;
      if (l == 0) {
        ko[si[i]] = 1.0f;
        avail[tw] &= ~(1ull << (i & 63));
      }
      float4 bi = sbL[i];
      float ai = (bi.z - bi.x + 1.0f) * (bi.w - bi.y + 1.0f);
      for (int w = tw; w <= wlast; w++) {
        unsigned long long aw = avail[w];
        if (!aw) continue;
        int col = (w << 6) + l;
        float4 bj = sbL[col];
        float iw = fminf(bi.z, bj.z) - fmaxf(bi.x, bj.x) + 1.0f;
        float ih = fminf(bi.w, bj.w) - fmaxf(bi.y, bj.y) + 1.0f;
        iw = fmaxf(iw, 0.f);
        ih = fmaxf(ih, 0.f);
        float inter = iw * ih;
        float aj = (bj.z - bj.x + 1.0f) * (bj.w - bj.y + 1.0f);
        float iou = inter / (ai + aj - inter);
        bool pr = (col > i) && (col < V) && (iou >= 0.4f);
        unsigned long long word = __ballot(pr);
        if (word && l == 0) avail[w] = aw & ~word;
      }
    }
  }
}

extern "C" void kernel_launch(void* const* d_in, const int* in_sizes, int n_in,
                              void* d_out, int out_size, void* d_ws, size_t ws_size,
                              hipStream_t stream) {
  const float* img = (const float*)d_in[0];
  const float* w1 = (const float*)d_in[1];
  const float* b1 = (const float*)d_in[2];
  const float* w2 = (const float*)d_in[3];
  const float* b2 = (const float*)d_in[4];
  const float* w3 = (const float*)d_in[5];
  const float* b3 = (const float*)d_in[6];
  const float* wd1 = (const float*)d_in[7];
  const float* bd1 = (const float*)d_in[8];
  const float* wd2 = (const float*)d_in[9];
  const float* bd2 = (const float*)d_in[10];

  float* ws = (float*)d_ws;
  float* a3 = ws + 0;                 // 1,971,200
  float* pd1 = ws + 3942400;          // 963*2048 = 1,972,224 (dead after reduce1a)
  float* partr = ws + 5914624;        // 16*2048
  float* d1t = ws + 5947392;          // 2048
  float* d2 = ws + 5949440;           // 307,200
  float* boxd = ws + 6256640;         // 307,200
  float4* sbf = (float4*)(ws + 6563840);  // 24*4800 float4 = 460,800 floats
  int* sidx = (int*)(ws + 7024640);   // 115,200
  int* cnt = (int*)(ws + 7139840);    // 24
  float* p1 = ws + 9324800;           // 2,306,304 pooled conv1
  float* p2 = ws + 16047104;          // 1,079,808 pooled conv2
  // mat overlays dead pd1 region: 24*1024*16 u64 = 786,432 floats
  unsigned long long* mat = (unsigned long long*)(ws + 3942400);

  float* pred = (float*)d_out;
  float* keep = pred + 307200;

  k_conv1p<<<dim3(8, 10, 8), 256, 0, stream>>>(img, w1, b1, p1);
  k_conv2p<<<dim3(8, 10, 8), 128, 0, stream>>>(p1, w2, b2, p2);
  k_conv3<<<dim3(4, 5, 16), 256, 0, stream>>>(p2, w3, b3, a3);
  k_dense1<<<963, 256, 0, stream>>>(a3, wd1, pd1);
  k_reduce1a<<<dim3(16, 8), 256, 0, stream>>>(pd1, partr);
  k_reduce1b<<<8, 256, 0, stream>>>(partr, bd1, d1t);
  k_dense2f<<<150, 256, 0, stream>>>(d1t, wd2, bd2, d2);
  k_transform<<<450, 256, 0, stream>>>(d2, pred, boxd, keep);
  k_nms_sort<<<24, 256, 0, stream>>>(boxd, cnt, sbf, sidx);
  k_iou_mat<<<dim3(24, 16), 256, 0, stream>>>(cnt, sbf, mat);
  k_nms_scan<<<24, 256, 0, stream>>>(cnt, mat, sbf, sidx, keep);
}

// Round 11
// 427.345 us; speedup vs baseline: 1.4676x; 1.0928x over previous
//
#include <hip/hip_runtime.h>
#include <stdint.h>

// Pipeline:
// img (8,160,240,3) -> conv1 6x6 (+fused 2x2 pool) -> (8,77,117,32)
// -> conv2 3x3 (+fused 2x2 pool) -> (8,37,57,64)
// -> conv3 3x3 -> (8,35,55,128) -> flatten 246400 -> dense 256 -> dense 38400
// (dense2 fused with reduce1b + predict_transform) -> pred + boxes
// NMS: sort -> grid-parallel IoU bit-matrix -> register-chain linear scan.

static __device__ __forceinline__ float sigmoidf_(float x) {
  return 1.0f / (1.0f + expf(-x));
}

// ---------------- conv1 6x6x3->32 + fused 2x2 maxpool ----------------
__global__ __launch_bounds__(256) void k_conv1p(const float* __restrict__ in,
    const float* __restrict__ w, const float* __restrict__ bias, float* __restrict__ out) {
  __shared__ float s_in[21 * 37 * 3];    // [y][x][c]
  __shared__ float s_w[6 * 6 * 3 * 32];  // [ky][kx][c][o]
  int tx = blockIdx.x, ty = blockIdx.y, n = blockIdx.z;
  int tid = threadIdx.x;
  int iy0 = ty * 16, ix0 = tx * 32;
  for (int idx = tid; idx < 3456; idx += 256) s_w[idx] = w[idx];
  for (int idx = tid; idx < 21 * 37 * 3; idx += 256) {
    int c = idx % 3;
    int rem = idx / 3;
    int x = rem % 37, y = rem / 37;
    int gy = iy0 + y, gx = ix0 + x;
    float v = 0.f;
    if (gy < 160 && gx < 240) v = in[((size_t)(n * 160 + gy) * 240 + gx) * 3 + c];
    s_in[idx] = v;
  }
  __syncthreads();

  int cg = tid >> 6;
  int l = tid & 63;
  int py = l >> 2;
  int px0 = (l & 3) * 8;

  float acc[8][8];
  float bj[8];
#pragma unroll
  for (int j = 0; j < 8; j++) bj[j] = bias[cg * 8 + j];
#pragma unroll
  for (int k = 0; k < 8; k++)
#pragma unroll
    for (int j = 0; j < 8; j++) acc[k][j] = bj[j];

#pragma unroll 1
  for (int ky = 0; ky < 6; ky++) {
#pragma unroll 1
    for (int kx = 0; kx < 6; kx++) {
#pragma unroll 1
      for (int c = 0; c < 3; c++) {
        const float* ib = s_in + ((py + ky) * 37 + px0 + kx) * 3 + c;
        float iv[8];
#pragma unroll
        for (int k = 0; k < 8; k++) iv[k] = ib[k * 3];
        const float* wb = s_w + ((ky * 6 + kx) * 3 + c) * 32 + cg * 8;
        float wv[8];
#pragma unroll
        for (int j = 0; j < 8; j++) wv[j] = wb[j];
#pragma unroll
        for (int k = 0; k < 8; k++)
#pragma unroll
          for (int j = 0; j < 8; j++) acc[k][j] = fmaf(iv[k], wv[j], acc[k][j]);
      }
    }
  }
  float pm[4][8];
#pragma unroll
  for (int kk = 0; kk < 4; kk++)
#pragma unroll
    for (int j = 0; j < 8; j++) pm[kk][j] = fmaxf(acc[2 * kk][j], acc[2 * kk + 1][j]);
#pragma unroll
  for (int kk = 0; kk < 4; kk++)
#pragma unroll
    for (int j = 0; j < 8; j++) {
      float o = __shfl_down(pm[kk][j], 4);
      pm[kk][j] = fmaxf(pm[kk][j], o);
    }
  if (!(py & 1)) {
    int pyp = ty * 8 + (py >> 1);
    if (pyp < 77) {
#pragma unroll
      for (int kk = 0; kk < 4; kk++) {
        int pxp = tx * 16 + (l & 3) * 4 + kk;
        if (pxp < 117) {
          float* op = out + ((size_t)(n * 77 + pyp) * 117 + pxp) * 32 + cg * 8;
          float4 v0, v1;
          v0.x = fmaxf(pm[kk][0], 0.f); v0.y = fmaxf(pm[kk][1], 0.f);
          v0.z = fmaxf(pm[kk][2], 0.f); v0.w = fmaxf(pm[kk][3], 0.f);
          v1.x = fmaxf(pm[kk][4], 0.f); v1.y = fmaxf(pm[kk][5], 0.f);
          v1.z = fmaxf(pm[kk][6], 0.f); v1.w = fmaxf(pm[kk][7], 0.f);
          ((float4*)op)[0] = v0;
          ((float4*)op)[1] = v1;
        }
      }
    }
  }
}

// ---------------- conv2 3x3x32->64 + fused 2x2 maxpool ----------------
__global__ __launch_bounds__(128) void k_conv2p(const float* __restrict__ in,
    const float* __restrict__ w, const float* __restrict__ bias, float* __restrict__ out) {
  __shared__ float s_in[32 * 10 * 18];  // [c][y][x]
  int tx = blockIdx.x, ty = blockIdx.y, n = blockIdx.z;
  int tid = threadIdx.x;
  int iy0 = ty * 8, ix0 = tx * 16;
  for (int idx = tid; idx < 10 * 18 * 32; idx += 128) {
    int c = idx & 31;
    int rem = idx >> 5;
    int x = rem % 18, y = rem / 18;
    int gy = iy0 + y, gx = ix0 + x;
    float v = 0.f;
    if (gy < 77 && gx < 117) v = in[((size_t)(n * 77 + gy) * 117 + gx) * 32 + c];
    s_in[c * 180 + y * 18 + x] = v;
  }
  __syncthreads();

  int cg = tid >> 4;
  int pg = tid & 15;
  int py = pg >> 1;
  int px0 = (pg & 1) * 8;

  float acc[8][8];
  float bj[8];
#pragma unroll
  for (int j = 0; j < 8; j++) bj[j] = bias[cg * 8 + j];
#pragma unroll
  for (int k = 0; k < 8; k++)
#pragma unroll
    for (int j = 0; j < 8; j++) acc[k][j] = bj[j];

#pragma unroll 1
  for (int ky = 0; ky < 3; ky++) {
#pragma unroll 1
    for (int kx = 0; kx < 3; kx++) {
      const float* wbase = w + (size_t)((ky * 3 + kx) * 32) * 64 + cg * 8;
      const float* ibase = s_in + (py + ky) * 18 + px0 + kx;
#pragma unroll 4
      for (int c = 0; c < 32; c++) {
        float4 wa = *(const float4*)(wbase + (size_t)c * 64);
        float4 wb = *(const float4*)(wbase + (size_t)c * 64 + 4);
        const float* ib = ibase + c * 180;
        float iv[8];
#pragma unroll
        for (int k = 0; k < 8; k++) iv[k] = ib[k];
#pragma unroll
        for (int k = 0; k < 8; k++) {
          acc[k][0] = fmaf(iv[k], wa.x, acc[k][0]);
          acc[k][1] = fmaf(iv[k], wa.y, acc[k][1]);
          acc[k][2] = fmaf(iv[k], wa.z, acc[k][2]);
          acc[k][3] = fmaf(iv[k], wa.w, acc[k][3]);
          acc[k][4] = fmaf(iv[k], wb.x, acc[k][4]);
          acc[k][5] = fmaf(iv[k], wb.y, acc[k][5]);
          acc[k][6] = fmaf(iv[k], wb.z, acc[k][6]);
          acc[k][7] = fmaf(iv[k], wb.w, acc[k][7]);
        }
      }
    }
  }
  float pm[4][8];
#pragma unroll
  for (int kk = 0; kk < 4; kk++)
#pragma unroll
    for (int j = 0; j < 8; j++) pm[kk][j] = fmaxf(acc[2 * kk][j], acc[2 * kk + 1][j]);
#pragma unroll
  for (int kk = 0; kk < 4; kk++)
#pragma unroll
    for (int j = 0; j < 8; j++) {
      float o = __shfl_down(pm[kk][j], 2);
      pm[kk][j] = fmaxf(pm[kk][j], o);
    }
  if (!(pg & 2)) {
    int pyp = ty * 4 + (py >> 1);
    if (pyp < 37) {
#pragma unroll
      for (int kk = 0; kk < 4; kk++) {
        int pxp = tx * 8 + (pg & 1) * 4 + kk;
        if (pxp < 57) {
          float* op = out + ((size_t)(n * 37 + pyp) * 57 + pxp) * 64 + cg * 8;
          float4 v0, v1;
          v0.x = fmaxf(pm[kk][0], 0.f); v0.y = fmaxf(pm[kk][1], 0.f);
          v0.z = fmaxf(pm[kk][2], 0.f); v0.w = fmaxf(pm[kk][3], 0.f);
          v1.x = fmaxf(pm[kk][4], 0.f); v1.y = fmaxf(pm[kk][5], 0.f);
          v1.z = fmaxf(pm[kk][6], 0.f); v1.w = fmaxf(pm[kk][7], 0.f);
          ((float4*)op)[0] = v0;
          ((float4*)op)[1] = v1;
        }
      }
    }
  }
}

// ---------------- conv3: 3x3x64 -> 128, channel-split x2 ----------------
__global__ __launch_bounds__(256) void k_conv3(const float* __restrict__ in,
    const float* __restrict__ w, const float* __restrict__ bias, float* __restrict__ out) {
  __shared__ float s_in[64 * 10 * 18];  // [c][y][x]
  int tx = blockIdx.x, ty = blockIdx.y, z = blockIdx.z;
  int n = z >> 1, h = z & 1;
  int tid = threadIdx.x;
  int iy0 = ty * 8, ix0 = tx * 16;
  for (int idx = tid; idx < 10 * 18 * 64; idx += 256) {
    int c = idx & 63;
    int rem = idx >> 6;
    int x = rem % 18, y = rem / 18;
    int gy = iy0 + y, gx = ix0 + x;
    float v = 0.f;
    if (gy < 37 && gx < 57) v = in[((size_t)(n * 37 + gy) * 57 + gx) * 64 + c];
    s_in[c * 180 + y * 18 + x] = v;
  }
  __syncthreads();

  int cg = tid >> 4;
  int pg = tid & 15;
  int py = pg >> 1;
  int px0 = (pg & 1) * 8;
  int ob = h * 64 + cg * 4;

  float acc[8][4];
  float bj[4];
#pragma unroll
  for (int j = 0; j < 4; j++) bj[j] = bias[ob + j];
#pragma unroll
  for (int k = 0; k < 8; k++)
#pragma unroll
    for (int j = 0; j < 4; j++) acc[k][j] = bj[j];

#pragma unroll 1
  for (int ky = 0; ky < 3; ky++) {
#pragma unroll 1
    for (int kx = 0; kx < 3; kx++) {
      const float* wbase = w + (size_t)((ky * 3 + kx) * 64) * 128 + ob;
      const float* ibase = s_in + (py + ky) * 18 + px0 + kx;
#pragma unroll 4
      for (int c = 0; c < 64; c++) {
        float4 wa = *(const float4*)(wbase + (size_t)c * 128);
        const float* ib = ibase + c * 180;
        float iv[8];
#pragma unroll
        for (int k = 0; k < 8; k++) iv[k] = ib[k];
#pragma unroll
        for (int k = 0; k < 8; k++) {
          acc[k][0] = fmaf(iv[k], wa.x, acc[k][0]);
          acc[k][1] = fmaf(iv[k], wa.y, acc[k][1]);
          acc[k][2] = fmaf(iv[k], wa.z, acc[k][2]);
          acc[k][3] = fmaf(iv[k], wa.w, acc[k][3]);
        }
      }
    }
  }
  int oy = iy0 + py;
  if (oy < 35) {
#pragma unroll
    for (int k = 0; k < 8; k++) {
      int ox = ix0 + px0 + k;
      if (ox < 55) {
        float* op = out + ((size_t)(n * 35 + oy) * 55 + ox) * 128 + ob;
        float4 v0;
        v0.x = fmaxf(acc[k][0], 0.f); v0.y = fmaxf(acc[k][1], 0.f);
        v0.z = fmaxf(acc[k][2], 0.f); v0.w = fmaxf(acc[k][3], 0.f);
        ((float4*)op)[0] = v0;
      }
    }
  }
}

// ---------------- dense1: (8,246400) @ (246400,256), split-K, x staged in LDS ----------------
__global__ __launch_bounds__(256) void k_dense1(const float* __restrict__ a3,
    const float* __restrict__ wd1, float* __restrict__ part) {
  __shared__ float red[4][64][33];  // +1 pad: kill 32-way bank conflicts
  __shared__ float s_x[256][8];
  int c = blockIdx.x;
  int tid = threadIdx.x;
  int c4 = tid & 63;
  int ks = tid >> 6;
  int k0 = c * 256;
  int kn = 246400 - k0;
  if (kn > 256) kn = 256;
  for (int idx = tid; idx < 2048; idx += 256) {
    int nn = idx >> 8, r = idx & 255;
    int rr = k0 + r;
    if (rr > 246399) rr = 246399;
    s_x[r][nn] = a3[(size_t)nn * 246400 + rr];
  }
  __syncthreads();
  float acc[8][4];
#pragma unroll
  for (int n = 0; n < 8; n++)
#pragma unroll
    for (int j = 0; j < 4; j++) acc[n][j] = 0.f;
  int kbeg = ks * 64;
  int kend = kbeg + 64;
  if (kend > kn) kend = kn;
#pragma unroll 4
  for (int kk = kbeg; kk < kend; kk++) {
    float4 wv = *(const float4*)(wd1 + (size_t)(k0 + kk) * 256 + c4 * 4);
    float4 xa = *(const float4*)&s_x[kk][0];
    float4 xb = *(const float4*)&s_x[kk][4];
    float xs[8] = {xa.x, xa.y, xa.z, xa.w, xb.x, xb.y, xb.z, xb.w};
#pragma unroll
    for (int n = 0; n < 8; n++) {
      acc[n][0] = fmaf(xs[n], wv.x, acc[n][0]);
      acc[n][1] = fmaf(xs[n], wv.y, acc[n][1]);
      acc[n][2] = fmaf(xs[n], wv.z, acc[n][2]);
      acc[n][3] = fmaf(xs[n], wv.w, acc[n][3]);
    }
  }
#pragma unroll
  for (int n = 0; n < 8; n++)
#pragma unroll
    for (int j = 0; j < 4; j++) red[ks][c4][n * 4 + j] = acc[n][j];
  __syncthreads();
  for (int o = tid; o < 2048; o += 256) {
    int col = o & 255, n = o >> 8;
    int cc = col >> 2, j = col & 3;
    float s = red[0][cc][n * 4 + j] + red[1][cc][n * 4 + j] +
              red[2][cc][n * 4 + j] + red[3][cc][n * 4 + j];
    part[(size_t)c * 2048 + n * 256 + col] = s;
  }
}

// ---------------- reduce1 stage A: 16 c-chunks x 2048, coalesced ----------------
__global__ __launch_bounds__(256) void k_reduce1a(const float* __restrict__ part,
    float* __restrict__ partr) {
  int bx = blockIdx.x;
  int t = blockIdx.y * 256 + threadIdx.x;
  int cbeg = bx * 61;
  int cend = cbeg + 61;
  if (cend > 963) cend = 963;
  float s = 0.f;
#pragma unroll 4
  for (int c = cbeg; c < cend; c++) s += part[(size_t)c * 2048 + t];
  partr[(size_t)bx * 2048 + t] = s;
}

// ---------------- dense2 + reduce1b + transform fused ----------------
// 300 blocks x 128 cols. Builds d1 (ReLU) in LDS from partr, GEMV over K=256,
// then transform epilogue: pred + boxd4 + meta (conf/cls) for the 8 cells.
__global__ __launch_bounds__(256) void k_dense2t(const float* __restrict__ partr,
    const float* __restrict__ bd1, const float* __restrict__ wd2,
    const float* __restrict__ bd2, float* __restrict__ pred,
    float4* __restrict__ boxd4, float* __restrict__ meta) {
  __shared__ float red[8][32][33];  // padded
  __shared__ float s_d1[256][8];
  int jb = blockIdx.x;  // 0..299
  int tid = threadIdx.x;
  for (int idx = tid; idx < 2048; idx += 256) {
    int n = idx >> 8, j = idx & 255;
    float s = 0.f;
#pragma unroll
    for (int b = 0; b < 16; b++) s += partr[b * 2048 + idx];
    s_d1[j][n] = fmaxf(s + bd1[j], 0.f);
  }
  __syncthreads();
  int c4 = tid & 31;   // 32 col-groups of 4 -> 128 cols
  int ks = tid >> 5;   // 8 row-groups of 32
  int j0 = jb * 128 + c4 * 4;
  float acc[8][4];
#pragma unroll
  for (int n = 0; n < 8; n++)
#pragma unroll
    for (int j = 0; j < 4; j++) acc[n][j] = 0.f;
#pragma unroll 4
  for (int kk = 0; kk < 32; kk++) {
    int row = ks * 32 + kk;
    float4 wv = *(const float4*)(wd2 + (size_t)row * 38400 + j0);
    float4 xa = *(const float4*)&s_d1[row][0];
    float4 xb = *(const float4*)&s_d1[row][4];
    float xs[8] = {xa.x, xa.y, xa.z, xa.w, xb.x, xb.y, xb.z, xb.w};
#pragma unroll
    for (int n = 0; n < 8; n++) {
      acc[n][0] = fmaf(xs[n], wv.x, acc[n][0]);
      acc[n][1] = fmaf(xs[n], wv.y, acc[n][1]);
      acc[n][2] = fmaf(xs[n], wv.z, acc[n][2]);
      acc[n][3] = fmaf(xs[n], wv.w, acc[n][3]);
    }
  }
#pragma unroll
  for (int n = 0; n < 8; n++)
#pragma unroll
    for (int j = 0; j < 4; j++) red[ks][c4][n * 4 + j] = acc[n][j];
  __syncthreads();
  if (tid >= 64) return;
  int n = tid >> 3, cc = tid & 7;
  int cell = jb * 8 + cc;  // 0..2399
  float v[16];
#pragma unroll
  for (int q = 0; q < 16; q++) {
    int lc = cc * 16 + q;
    int cq = lc >> 2, jq = lc & 3;
    float s = 0.f;
#pragma unroll
    for (int g = 0; g < 8; g++) s += red[g][cq][n * 4 + jq];
    v[q] = s + bd2[jb * 128 + lc];
  }
  float gx = (float)(cell % 60), gy = (float)(cell / 60);
  float o[16];
  o[0] = (sigmoidf_(v[0]) + gx) * 4.0f;
  o[1] = (sigmoidf_(v[1]) + gy) * 4.0f;
  o[2] = expf(v[2]) * 60.0f * 4.0f;
  o[3] = expf(v[3]) * 30.0f * 4.0f;
  o[4] = sigmoidf_(v[4]);
  o[5] = sigmoidf_(v[5]);
  o[6] = sigmoidf_(v[6]);
  o[7] = sigmoidf_(v[7]);
  o[8] = (v[8] + gx) * 4.0f;
  o[9] = (v[9] + gy) * 4.0f;
  o[10] = expf(v[10]) * 20.0f * 4.0f;
  o[11] = expf(v[11]) * 40.0f * 4.0f;
  o[12] = v[12];
  o[13] = sigmoidf_(v[13]);
  o[14] = sigmoidf_(v[14]);
  o[15] = sigmoidf_(v[15]);
  float* op = pred + ((size_t)n * 2400 + cell) * 16;
#pragma unroll
  for (int q4 = 0; q4 < 4; q4++) {
    float4 w4;
    w4.x = o[q4 * 4 + 0]; w4.y = o[q4 * 4 + 1];
    w4.z = o[q4 * 4 + 2]; w4.w = o[q4 * 4 + 3];
    ((float4*)op)[q4] = w4;
  }
#pragma unroll
  for (int h = 0; h < 2; h++) {
    int b = n * 4800 + h * 2400 + cell;
    float X = o[h * 8 + 0], Y = o[h * 8 + 1], W = o[h * 8 + 2], H = o[h * 8 + 3];
    float conf = o[h * 8 + 4];
    float c0 = o[h * 8 + 5], c1 = o[h * 8 + 6], c2 = o[h * 8 + 7];
    int cls = 0; float best = c0;
    if (c1 > best) { best = c1; cls = 1; }
    if (c2 > best) { best = c2; cls = 2; }
    float x1 = X - W / 2.0f, y1 = Y - H / 2.0f;
    float x2 = X + W / 2.0f, y2 = Y + H / 2.0f;
    boxd4[b] = make_float4(x1, y1, x2, y2);
    meta[2 * b] = conf;
    ((int*)meta)[2 * b + 1] = cls;
  }
}

// ---------------- NMS stage 1: zero keep + compact + sort -> sorted arrays ----------------
__global__ __launch_bounds__(256) void k_nms_sort(const float4* __restrict__ boxd4,
    const float* __restrict__ meta, int* __restrict__ cnt,
    float4* __restrict__ sbf, int* __restrict__ sidx, float* __restrict__ keep_out) {
  __shared__ unsigned long long key[8192];
  __shared__ int scnt;
  int bid = blockIdx.x;  // 0..23
  int n = bid / 3, c = bid - n * 3;
  int tid = threadIdx.x;
  float* ko = keep_out + (size_t)bid * 4800;
  for (int s = tid; s < 4800; s += 256) ko[s] = 0.f;  // zero own slice
  if (tid == 0) scnt = 0;
  __syncthreads();

  const float* mt = meta + (size_t)n * 9600;
  for (int p = tid; p < 4800; p += 256) {
    float2 m = ((const float2*)mt)[p];
    float conf = m.x;
    int cls = __float_as_int(m.y);
    if (conf > 0.5f && cls == c) {
      int slot = atomicAdd(&scnt, 1);
      unsigned u = __float_as_uint(conf);
      unsigned asc = (u & 0x80000000u) ? ~u : (u | 0x80000000u);
      key[slot] = (((unsigned long long)(~asc)) << 32) | (unsigned)p;
    }
  }
  __syncthreads();
  int V = scnt;
  if (tid == 0) cnt[bid] = V;
  if (V == 0) return;
  int Vp2 = 1;
  while (Vp2 < V) Vp2 <<= 1;
  for (int s = V + tid; s < Vp2; s += 256) key[s] = ~0ull;

  // bitonic sort ascending -> score desc, idx asc (stable argsort(-score))
  for (int k = 2; k <= Vp2; k <<= 1) {
    for (int j = k >> 1; j > 0; j >>= 1) {
      __syncthreads();
      int jm = j - 1;
      for (int t2 = tid; t2 < (Vp2 >> 1); t2 += 256) {
        int i = ((t2 & ~jm) << 1) | (t2 & jm);
        int q = i | j;
        bool up = ((i & k) == 0);
        unsigned long long a = key[i], b2 = key[q];
        if ((a > b2) == up) { key[i] = b2; key[q] = a; }
      }
    }
  }
  __syncthreads();
  float4* sb = sbf + (size_t)bid * 4800;
  int* si = sidx + (size_t)bid * 4800;
  const float4* bsrc = boxd4 + (size_t)n * 4800;
  for (int s = tid; s < V; s += 256) {
    unsigned p = (unsigned)(key[s] & 0xFFFFFFFFull);
    sb[s] = bsrc[p];
    si[s] = (int)p;
  }
}

// ---------------- NMS stage 2: grid-parallel suppression bit-matrix ----------------
__global__ __launch_bounds__(256) void k_iou_mat(const int* __restrict__ cnt,
    const float4* __restrict__ sbf, unsigned long long* __restrict__ mat) {
  int nc = blockIdx.x;
  int w = blockIdx.y;
  int V = cnt[nc];
  if (V == 0 || V > 1024) return;
  int W = (V + 63) >> 6;
  if (w >= W) return;
  int tid = threadIdx.x;
  int l = tid & 63, wv = tid >> 6;
  const float4* sb = sbf + (size_t)nc * 4800;
  int col = (w << 6) + l;
  float4 bj = sb[col < V ? col : (V - 1)];
  float aj = (bj.z - bj.x + 1.0f) * (bj.w - bj.y + 1.0f);
  unsigned long long* mrow = mat + (size_t)nc * 1024 * 16 + w;
  for (int i = wv; i < V; i += 4) {
    float4 bi = sb[i];  // wave-uniform, L2-hot
    float iw = fminf(bi.z, bj.z) - fmaxf(bi.x, bj.x) + 1.0f;
    float ih = fminf(bi.w, bj.w) - fmaxf(bi.y, bj.y) + 1.0f;
    iw = fmaxf(iw, 0.f);
    ih = fmaxf(ih, 0.f);
    float inter = iw * ih;
    float ai = (bi.z - bi.x + 1.0f) * (bi.w - bi.y + 1.0f);
    float iou = inter / (ai + aj - inter);
    bool pr = (col > i) && (col < V) && (iou >= 0.4f);
    unsigned long long word = __ballot(pr);
    if (l == 0) mrow[(size_t)i * 16] = word;
  }
}

// ---------------- NMS stage 3: linear greedy scan, VALU-only serial chain ----------------
__global__ __launch_bounds__(256) void k_nms_scan(const int* __restrict__ cnt,
    const unsigned long long* __restrict__ mat, const float4* __restrict__ sbf,
    const int* __restrict__ sidx, float* __restrict__ keep_out) {
  __shared__ float4 sbL[4800];            // slow-path staging
  __shared__ unsigned long long avail[75];
  int nc = blockIdx.x;
  int V = cnt[nc];
  if (V == 0) return;
  int tid = threadIdx.x;
  float* ko = keep_out + (size_t)nc * 4800;
  const int* si = sidx + (size_t)nc * 4800;

  if (V <= 1024) {
    if (tid >= 64) return;
    int l = tid;
    int W = (V + 63) >> 6;
    const unsigned long long* mbase = mat + (size_t)nc * 1024 * 16;
    bool act = (l < W);
    unsigned long long av = 0ull;  // lane l holds avail word l
    if (act) {
      int rem = V - (l << 6);
      av = (rem >= 64) ? ~0ull : ((1ull << rem) - 1ull);
    }
    unsigned long long mA[16], mB[16];
#pragma unroll
    for (int k = 0; k < 16; k++)
      mA[k] = (act && k < V) ? mbase[(size_t)k * 16 + l] : 0ull;
    for (int i0 = 0; i0 < V; i0 += 16) {
      int nx = i0 + 16;
#pragma unroll
      for (int k = 0; k < 16; k++)
        mB[k] = (act && (nx + k) < V) ? mbase[(size_t)(nx + k) * 16 + l] : 0ull;
      int wi = i0 >> 6;
      unsigned long long mloc[16];
#pragma unroll
      for (int k = 0; k < 16; k++) mloc[k] = __shfl(mA[k], wi, 64);
      unsigned long long cur = __shfl(av, wi, 64);
      unsigned alive = 0;
#pragma unroll
      for (int k = 0; k < 16; k++) {
        int i = i0 + k;
        if (i < V && ((cur >> (i & 63)) & 1ull)) {
          alive |= 1u << k;
          cur &= ~mloc[k];
        }
      }
#pragma unroll
      for (int k = 0; k < 16; k++)
        if ((alive >> k) & 1u) av &= ~mA[k];
      if (l < 16 && ((alive >> l) & 1u) && (i0 + l) < V) ko[si[i0 + l]] = 1.0f;
#pragma unroll
      for (int k = 0; k < 16; k++) mA[k] = mB[k];
    }
    return;
  }

  // slow path (V > 1024): r6-validated single-wave greedy
  {
    const float4* sb = sbf + (size_t)nc * 4800;
    for (int s = tid; s < V; s += 256) sbL[s] = sb[s];
    for (int w = tid; w < 75; w += 256) {
      int rem = V - (w << 6);
      avail[w] = (rem >= 64) ? ~0ull : (rem <= 0 ? 0ull : ((1ull << rem) - 1ull));
    }
    __syncthreads();
    if (tid >= 64) return;
    int l = tid;
    int wlast = (V - 1) >> 6;
    for (;;) {
      int cand = 0x7FFFFFFF;
      unsigned long long a0 = avail[l];
      if (a0) cand = (l << 6) + __ffsll((long long)a0) - 1;
      if (l < 11) {
        unsigned long long a1 = avail[64 + l];
        if (a1) {
          int c2 = ((64 + l) << 6) + __ffsll((long long)a1) - 1;
          if (c2 < cand) cand = c2;
        }
      }
#pragma unroll
      for (int off = 32; off > 0; off >>= 1) {
        int o = __shfl_xor(cand, off, 64);
        if (o < cand) cand = o;
      }
      if (cand == 0x7FFFFFFF) break;
      int i = cand;
      int tw = i >> 6;
      if (l == 0) {
        ko[si[i]] = 1.0f;
        avail[tw] &= ~(1ull << (i & 63));
      }
      float4 bi = sbL[i];
      float ai = (bi.z - bi.x + 1.0f) * (bi.w - bi.y + 1.0f);
      for (int w = tw; w <= wlast; w++) {
        unsigned long long aw = avail[w];
        if (!aw) continue;
        int col = (w << 6) + l;
        float4 bj = sbL[col];
        float iw = fminf(bi.z, bj.z) - fmaxf(bi.x, bj.x) + 1.0f;
        float ih = fminf(bi.w, bj.w) - fmaxf(bi.y, bj.y) + 1.0f;
        iw = fmaxf(iw, 0.f);
        ih = fmaxf(ih, 0.f);
        float inter = iw * ih;
        float aj = (bj.z - bj.x + 1.0f) * (bj.w - bj.y + 1.0f);
        float iou = inter / (ai + aj - inter);
        bool pr = (col > i) && (col < V) && (iou >= 0.4f);
        unsigned long long word = __ballot(pr);
        if (word && l == 0) avail[w] = aw & ~word;
      }
    }
  }
}

extern "C" void kernel_launch(void* const* d_in, const int* in_sizes, int n_in,
                              void* d_out, int out_size, void* d_ws, size_t ws_size,
                              hipStream_t stream) {
  const float* img = (const float*)d_in[0];
  const float* w1 = (const float*)d_in[1];
  const float* b1 = (const float*)d_in[2];
  const float* w2 = (const float*)d_in[3];
  const float* b2 = (const float*)d_in[4];
  const float* w3 = (const float*)d_in[5];
  const float* b3 = (const float*)d_in[6];
  const float* wd1 = (const float*)d_in[7];
  const float* bd1 = (const float*)d_in[8];
  const float* wd2 = (const float*)d_in[9];
  const float* bd2 = (const float*)d_in[10];

  float* ws = (float*)d_ws;
  float* a3 = ws + 0;                       // 1,971,200
  float* pd1 = ws + 3942400;                // 1,972,224 (dead after reduce1a)
  float* partr = ws + 5914624;              // 32,768
  float4* boxd4 = (float4*)(ws + 5947392);  // 38400 float4 = 153,600 floats
  float* meta = ws + 6100992;               // 76,800
  float4* sbf = (float4*)(ws + 6177792);    // 460,800
  int* sidx = (int*)(ws + 6638592);         // 115,200
  int* cnt = (int*)(ws + 6753792);          // 24
  float* p1 = ws + 9324800;                 // 2,306,304 pooled conv1
  float* p2 = ws + 16047104;                // 1,079,808 pooled conv2
  // mat overlays dead pd1 region: 24*1024*16 u64 = 786,432 floats
  unsigned long long* mat = (unsigned long long*)(ws + 3942400);

  float* pred = (float*)d_out;
  float* keep = pred + 307200;

  k_conv1p<<<dim3(8, 10, 8), 256, 0, stream>>>(img, w1, b1, p1);
  k_conv2p<<<dim3(8, 10, 8), 128, 0, stream>>>(p1, w2, b2, p2);
  k_conv3<<<dim3(4, 5, 16), 256, 0, stream>>>(p2, w3, b3, a3);
  k_dense1<<<963, 256, 0, stream>>>(a3, wd1, pd1);
  k_reduce1a<<<dim3(16, 8), 256, 0, stream>>>(pd1, partr);
  k_dense2t<<<300, 256, 0, stream>>>(partr, bd1, wd2, bd2, pred, boxd4, meta);
  k_nms_sort<<<24, 256, 0, stream>>>(boxd4, meta, cnt, sbf, sidx, keep);
  k_iou_mat<<<dim3(24, 16), 256, 0, stream>>>(cnt, sbf, mat);
  k_nms_scan<<<24, 256, 0, stream>>>(cnt, mat, sbf, sidx, keep);
}

// Round 12
// 358.836 us; speedup vs baseline: 1.7477x; 1.1909x over previous
//
#include <hip/hip_runtime.h>
#include <stdint.h>

// Pipeline:
// img (8,160,240,3) -> conv1 6x6 (+fused 2x2 pool) -> (8,77,117,32)
// -> conv2 3x3 (+fused 2x2 pool) -> (8,37,57,64)
// -> conv3 3x3 -> (8,35,55,128) -> flatten 246400 -> dense 256 -> dense 38400
// (dense2 fused with reduce1b + predict_transform) -> pred + boxes
// NMS: sort -> grid-parallel IoU bit-matrix -> register-chain linear scan.

static __device__ __forceinline__ float sigmoidf_(float x) {
  return 1.0f / (1.0f + expf(-x));
}

// ---------------- conv1 6x6x3->32 + fused 2x2 maxpool ----------------
__global__ __launch_bounds__(256) void k_conv1p(const float* __restrict__ in,
    const float* __restrict__ w, const float* __restrict__ bias, float* __restrict__ out) {
  __shared__ float s_in[21 * 37 * 3];    // [y][x][c]
  __shared__ float s_w[6 * 6 * 3 * 32];  // [ky][kx][c][o]
  int tx = blockIdx.x, ty = blockIdx.y, n = blockIdx.z;
  int tid = threadIdx.x;
  int iy0 = ty * 16, ix0 = tx * 32;
  for (int idx = tid; idx < 3456; idx += 256) s_w[idx] = w[idx];
  for (int idx = tid; idx < 21 * 37 * 3; idx += 256) {
    int c = idx % 3;
    int rem = idx / 3;
    int x = rem % 37, y = rem / 37;
    int gy = iy0 + y, gx = ix0 + x;
    float v = 0.f;
    if (gy < 160 && gx < 240) v = in[((size_t)(n * 160 + gy) * 240 + gx) * 3 + c];
    s_in[idx] = v;
  }
  __syncthreads();

  int cg = tid >> 6;
  int l = tid & 63;
  int py = l >> 2;
  int px0 = (l & 3) * 8;

  float acc[8][8];
  float bj[8];
#pragma unroll
  for (int j = 0; j < 8; j++) bj[j] = bias[cg * 8 + j];
#pragma unroll
  for (int k = 0; k < 8; k++)
#pragma unroll
    for (int j = 0; j < 8; j++) acc[k][j] = bj[j];

#pragma unroll 1
  for (int ky = 0; ky < 6; ky++) {
#pragma unroll 1
    for (int kx = 0; kx < 6; kx++) {
#pragma unroll 1
      for (int c = 0; c < 3; c++) {
        const float* ib = s_in + ((py + ky) * 37 + px0 + kx) * 3 + c;
        float iv[8];
#pragma unroll
        for (int k = 0; k < 8; k++) iv[k] = ib[k * 3];
        const float* wb = s_w + ((ky * 6 + kx) * 3 + c) * 32 + cg * 8;
        float wv[8];
#pragma unroll
        for (int j = 0; j < 8; j++) wv[j] = wb[j];
#pragma unroll
        for (int k = 0; k < 8; k++)
#pragma unroll
          for (int j = 0; j < 8; j++) acc[k][j] = fmaf(iv[k], wv[j], acc[k][j]);
      }
    }
  }
  float pm[4][8];
#pragma unroll
  for (int kk = 0; kk < 4; kk++)
#pragma unroll
    for (int j = 0; j < 8; j++) pm[kk][j] = fmaxf(acc[2 * kk][j], acc[2 * kk + 1][j]);
#pragma unroll
  for (int kk = 0; kk < 4; kk++)
#pragma unroll
    for (int j = 0; j < 8; j++) {
      float o = __shfl_down(pm[kk][j], 4);
      pm[kk][j] = fmaxf(pm[kk][j], o);
    }
  if (!(py & 1)) {
    int pyp = ty * 8 + (py >> 1);
    if (pyp < 77) {
#pragma unroll
      for (int kk = 0; kk < 4; kk++) {
        int pxp = tx * 16 + (l & 3) * 4 + kk;
        if (pxp < 117) {
          float* op = out + ((size_t)(n * 77 + pyp) * 117 + pxp) * 32 + cg * 8;
          float4 v0, v1;
          v0.x = fmaxf(pm[kk][0], 0.f); v0.y = fmaxf(pm[kk][1], 0.f);
          v0.z = fmaxf(pm[kk][2], 0.f); v0.w = fmaxf(pm[kk][3], 0.f);
          v1.x = fmaxf(pm[kk][4], 0.f); v1.y = fmaxf(pm[kk][5], 0.f);
          v1.z = fmaxf(pm[kk][6], 0.f); v1.w = fmaxf(pm[kk][7], 0.f);
          ((float4*)op)[0] = v0;
          ((float4*)op)[1] = v1;
        }
      }
    }
  }
}

// ---------------- conv2 3x3x32->64 + fused 2x2 maxpool (256 thr, 4ch/thread) ------
__global__ __launch_bounds__(256) void k_conv2p(const float* __restrict__ in,
    const float* __restrict__ w, const float* __restrict__ bias, float* __restrict__ out) {
  __shared__ float s_in[32 * 10 * 18];  // [c][y][x]
  int tx = blockIdx.x, ty = blockIdx.y, n = blockIdx.z;
  int tid = threadIdx.x;
  int iy0 = ty * 8, ix0 = tx * 16;
  for (int idx = tid; idx < 10 * 18 * 32; idx += 256) {
    int c = idx & 31;
    int rem = idx >> 5;
    int x = rem % 18, y = rem / 18;
    int gy = iy0 + y, gx = ix0 + x;
    float v = 0.f;
    if (gy < 77 && gx < 117) v = in[((size_t)(n * 77 + gy) * 117 + gx) * 32 + c];
    s_in[c * 180 + y * 18 + x] = v;
  }
  __syncthreads();

  int cg = tid >> 4;   // 16 groups x 4 out-ch
  int pg = tid & 15;
  int py = pg >> 1;
  int px0 = (pg & 1) * 8;

  float acc[8][4];
  float bj[4];
#pragma unroll
  for (int j = 0; j < 4; j++) bj[j] = bias[cg * 4 + j];
#pragma unroll
  for (int k = 0; k < 8; k++)
#pragma unroll
    for (int j = 0; j < 4; j++) acc[k][j] = bj[j];

#pragma unroll 1
  for (int ky = 0; ky < 3; ky++) {
#pragma unroll 1
    for (int kx = 0; kx < 3; kx++) {
      const float* wbase = w + (size_t)((ky * 3 + kx) * 32) * 64 + cg * 4;
      const float* ibase = s_in + (py + ky) * 18 + px0 + kx;
#pragma unroll 4
      for (int c = 0; c < 32; c++) {
        float4 wa = *(const float4*)(wbase + (size_t)c * 64);
        const float* ib = ibase + c * 180;
        float iv[8];
#pragma unroll
        for (int k = 0; k < 8; k++) iv[k] = ib[k];
#pragma unroll
        for (int k = 0; k < 8; k++) {
          acc[k][0] = fmaf(iv[k], wa.x, acc[k][0]);
          acc[k][1] = fmaf(iv[k], wa.y, acc[k][1]);
          acc[k][2] = fmaf(iv[k], wa.z, acc[k][2]);
          acc[k][3] = fmaf(iv[k], wa.w, acc[k][3]);
        }
      }
    }
  }
  float pm[4][4];
#pragma unroll
  for (int kk = 0; kk < 4; kk++)
#pragma unroll
    for (int j = 0; j < 4; j++) pm[kk][j] = fmaxf(acc[2 * kk][j], acc[2 * kk + 1][j]);
#pragma unroll
  for (int kk = 0; kk < 4; kk++)
#pragma unroll
    for (int j = 0; j < 4; j++) {
      float o = __shfl_down(pm[kk][j], 2);
      pm[kk][j] = fmaxf(pm[kk][j], o);
    }
  if (!(pg & 2)) {
    int pyp = ty * 4 + (py >> 1);
    if (pyp < 37) {
#pragma unroll
      for (int kk = 0; kk < 4; kk++) {
        int pxp = tx * 8 + (pg & 1) * 4 + kk;
        if (pxp < 57) {
          float* op = out + ((size_t)(n * 37 + pyp) * 57 + pxp) * 64 + cg * 4;
          float4 v0;
          v0.x = fmaxf(pm[kk][0], 0.f); v0.y = fmaxf(pm[kk][1], 0.f);
          v0.z = fmaxf(pm[kk][2], 0.f); v0.w = fmaxf(pm[kk][3], 0.f);
          ((float4*)op)[0] = v0;
        }
      }
    }
  }
}

// ---------------- conv3: 3x3x64 -> 128, 4-row tiles, channel-split x2 ----------------
// grid (4, 9, 16): z = n*2 + half; 256 thr: cg=tid>>4 (16 grp x 4ch),
// pg=tid&15: py=pg>>2 (0..3), px0=(pg&3)*4 (4 px each).
__global__ __launch_bounds__(256) void k_conv3(const float* __restrict__ in,
    const float* __restrict__ w, const float* __restrict__ bias, float* __restrict__ out) {
  __shared__ float s_in[64 * 6 * 18];  // [c][y][x]
  int tx = blockIdx.x, ty = blockIdx.y, z = blockIdx.z;
  int n = z >> 1, h = z & 1;
  int tid = threadIdx.x;
  int iy0 = ty * 4, ix0 = tx * 16;
  for (int idx = tid; idx < 6 * 18 * 64; idx += 256) {
    int c = idx & 63;
    int rem = idx >> 6;
    int x = rem % 18, y = rem / 18;
    int gy = iy0 + y, gx = ix0 + x;
    float v = 0.f;
    if (gy < 37 && gx < 57) v = in[((size_t)(n * 37 + gy) * 57 + gx) * 64 + c];
    s_in[c * 108 + y * 18 + x] = v;
  }
  __syncthreads();

  int cg = tid >> 4;
  int pg = tid & 15;
  int py = pg >> 2;
  int px0 = (pg & 3) * 4;
  int ob = h * 64 + cg * 4;

  float acc[4][4];
  float bj[4];
#pragma unroll
  for (int j = 0; j < 4; j++) bj[j] = bias[ob + j];
#pragma unroll
  for (int k = 0; k < 4; k++)
#pragma unroll
    for (int j = 0; j < 4; j++) acc[k][j] = bj[j];

#pragma unroll 1
  for (int ky = 0; ky < 3; ky++) {
#pragma unroll 1
    for (int kx = 0; kx < 3; kx++) {
      const float* wbase = w + (size_t)((ky * 3 + kx) * 64) * 128 + ob;
      const float* ibase = s_in + (py + ky) * 18 + px0 + kx;
#pragma unroll 4
      for (int c = 0; c < 64; c++) {
        float4 wa = *(const float4*)(wbase + (size_t)c * 128);
        const float* ib = ibase + c * 108;
        float iv[4];
#pragma unroll
        for (int k = 0; k < 4; k++) iv[k] = ib[k];
#pragma unroll
        for (int k = 0; k < 4; k++) {
          acc[k][0] = fmaf(iv[k], wa.x, acc[k][0]);
          acc[k][1] = fmaf(iv[k], wa.y, acc[k][1]);
          acc[k][2] = fmaf(iv[k], wa.z, acc[k][2]);
          acc[k][3] = fmaf(iv[k], wa.w, acc[k][3]);
        }
      }
    }
  }
  int oy = iy0 + py;
  if (oy < 35) {
#pragma unroll
    for (int k = 0; k < 4; k++) {
      int ox = ix0 + px0 + k;
      if (ox < 55) {
        float* op = out + ((size_t)(n * 35 + oy) * 55 + ox) * 128 + ob;
        float4 v0;
        v0.x = fmaxf(acc[k][0], 0.f); v0.y = fmaxf(acc[k][1], 0.f);
        v0.z = fmaxf(acc[k][2], 0.f); v0.w = fmaxf(acc[k][3], 0.f);
        ((float4*)op)[0] = v0;
      }
    }
  }
}

// ---------------- dense1: (8,246400) @ (246400,256), split-K, x staged in LDS ----------------
__global__ __launch_bounds__(256) void k_dense1(const float* __restrict__ a3,
    const float* __restrict__ wd1, float* __restrict__ part) {
  __shared__ float red[4][64][33];  // +1 pad: kill 32-way bank conflicts
  __shared__ float s_x[256][8];
  int c = blockIdx.x;
  int tid = threadIdx.x;
  int c4 = tid & 63;
  int ks = tid >> 6;
  int k0 = c * 256;
  int kn = 246400 - k0;
  if (kn > 256) kn = 256;
  for (int idx = tid; idx < 2048; idx += 256) {
    int nn = idx >> 8, r = idx & 255;
    int rr = k0 + r;
    if (rr > 246399) rr = 246399;
    s_x[r][nn] = a3[(size_t)nn * 246400 + rr];
  }
  __syncthreads();
  float acc[8][4];
#pragma unroll
  for (int n = 0; n < 8; n++)
#pragma unroll
    for (int j = 0; j < 4; j++) acc[n][j] = 0.f;
  int kbeg = ks * 64;
  int kend = kbeg + 64;
  if (kend > kn) kend = kn;
#pragma unroll 8
  for (int kk = kbeg; kk < kend; kk++) {
    float4 wv = *(const float4*)(wd1 + (size_t)(k0 + kk) * 256 + c4 * 4);
    float4 xa = *(const float4*)&s_x[kk][0];
    float4 xb = *(const float4*)&s_x[kk][4];
    float xs[8] = {xa.x, xa.y, xa.z, xa.w, xb.x, xb.y, xb.z, xb.w};
#pragma unroll
    for (int n = 0; n < 8; n++) {
      acc[n][0] = fmaf(xs[n], wv.x, acc[n][0]);
      acc[n][1] = fmaf(xs[n], wv.y, acc[n][1]);
      acc[n][2] = fmaf(xs[n], wv.z, acc[n][2]);
      acc[n][3] = fmaf(xs[n], wv.w, acc[n][3]);
    }
  }
#pragma unroll
  for (int n = 0; n < 8; n++)
#pragma unroll
    for (int j = 0; j < 4; j++) red[ks][c4][n * 4 + j] = acc[n][j];
  __syncthreads();
  for (int o = tid; o < 2048; o += 256) {
    int col = o & 255, n = o >> 8;
    int cc = col >> 2, j = col & 3;
    float s = red[0][cc][n * 4 + j] + red[1][cc][n * 4 + j] +
              red[2][cc][n * 4 + j] + red[3][cc][n * 4 + j];
    part[(size_t)c * 2048 + n * 256 + col] = s;
  }
}

// ---------------- reduce1 stage A: 16 c-chunks x 2048, coalesced ----------------
__global__ __launch_bounds__(256) void k_reduce1a(const float* __restrict__ part,
    float* __restrict__ partr) {
  int bx = blockIdx.x;
  int t = blockIdx.y * 256 + threadIdx.x;
  int cbeg = bx * 61;
  int cend = cbeg + 61;
  if (cend > 963) cend = 963;
  float s = 0.f;
#pragma unroll 4
  for (int c = cbeg; c < cend; c++) s += part[(size_t)c * 2048 + t];
  partr[(size_t)bx * 2048 + t] = s;
}

// ---------------- dense2 + reduce1b + transform fused ----------------
__global__ __launch_bounds__(256) void k_dense2t(const float* __restrict__ partr,
    const float* __restrict__ bd1, const float* __restrict__ wd2,
    const float* __restrict__ bd2, float* __restrict__ pred,
    float4* __restrict__ boxd4, float* __restrict__ meta) {
  __shared__ float red[8][32][33];  // padded
  __shared__ float s_d1[256][8];
  int jb = blockIdx.x;  // 0..299
  int tid = threadIdx.x;
  for (int idx = tid; idx < 2048; idx += 256) {
    int n = idx >> 8, j = idx & 255;
    float s = 0.f;
#pragma unroll
    for (int b = 0; b < 16; b++) s += partr[b * 2048 + idx];
    s_d1[j][n] = fmaxf(s + bd1[j], 0.f);
  }
  __syncthreads();
  int c4 = tid & 31;
  int ks = tid >> 5;
  int j0 = jb * 128 + c4 * 4;
  float acc[8][4];
#pragma unroll
  for (int n = 0; n < 8; n++)
#pragma unroll
    for (int j = 0; j < 4; j++) acc[n][j] = 0.f;
#pragma unroll 4
  for (int kk = 0; kk < 32; kk++) {
    int row = ks * 32 + kk;
    float4 wv = *(const float4*)(wd2 + (size_t)row * 38400 + j0);
    float4 xa = *(const float4*)&s_d1[row][0];
    float4 xb = *(const float4*)&s_d1[row][4];
    float xs[8] = {xa.x, xa.y, xa.z, xa.w, xb.x, xb.y, xb.z, xb.w};
#pragma unroll
    for (int n = 0; n < 8; n++) {
      acc[n][0] = fmaf(xs[n], wv.x, acc[n][0]);
      acc[n][1] = fmaf(xs[n], wv.y, acc[n][1]);
      acc[n][2] = fmaf(xs[n], wv.z, acc[n][2]);
      acc[n][3] = fmaf(xs[n], wv.w, acc[n][3]);
    }
  }
#pragma unroll
  for (int n = 0; n < 8; n++)
#pragma unroll
    for (int j = 0; j < 4; j++) red[ks][c4][n * 4 + j] = acc[n][j];
  __syncthreads();
  if (tid >= 64) return;
  int n = tid >> 3, cc = tid & 7;
  int cell = jb * 8 + cc;  // 0..2399
  float v[16];
#pragma unroll
  for (int q = 0; q < 16; q++) {
    int lc = cc * 16 + q;
    int cq = lc >> 2, jq = lc & 3;
    float s = 0.f;
#pragma unroll
    for (int g = 0; g < 8; g++) s += red[g][cq][n * 4 + jq];
    v[q] = s + bd2[jb * 128 + lc];
  }
  float gx = (float)(cell % 60), gy = (float)(cell / 60);
  float o[16];
  o[0] = (sigmoidf_(v[0]) + gx) * 4.0f;
  o[1] = (sigmoidf_(v[1]) + gy) * 4.0f;
  o[2] = expf(v[2]) * 60.0f * 4.0f;
  o[3] = expf(v[3]) * 30.0f * 4.0f;
  o[4] = sigmoidf_(v[4]);
  o[5] = sigmoidf_(v[5]);
  o[6] = sigmoidf_(v[6]);
  o[7] = sigmoidf_(v[7]);
  o[8] = (v[8] + gx) * 4.0f;
  o[9] = (v[9] + gy) * 4.0f;
  o[10] = expf(v[10]) * 20.0f * 4.0f;
  o[11] = expf(v[11]) * 40.0f * 4.0f;
  o[12] = v[12];
  o[13] = sigmoidf_(v[13]);
  o[14] = sigmoidf_(v[14]);
  o[15] = sigmoidf_(v[15]);
  float* op = pred + ((size_t)n * 2400 + cell) * 16;
#pragma unroll
  for (int q4 = 0; q4 < 4; q4++) {
    float4 w4;
    w4.x = o[q4 * 4 + 0]; w4.y = o[q4 * 4 + 1];
    w4.z = o[q4 * 4 + 2]; w4.w = o[q4 * 4 + 3];
    ((float4*)op)[q4] = w4;
  }
#pragma unroll
  for (int h = 0; h < 2; h++) {
    int b = n * 4800 + h * 2400 + cell;
    float X = o[h * 8 + 0], Y = o[h * 8 + 1], W = o[h * 8 + 2], H = o[h * 8 + 3];
    float conf = o[h * 8 + 4];
    float c0 = o[h * 8 + 5], c1 = o[h * 8 + 6], c2 = o[h * 8 + 7];
    int cls = 0; float best = c0;
    if (c1 > best) { best = c1; cls = 1; }
    if (c2 > best) { best = c2; cls = 2; }
    float x1 = X - W / 2.0f, y1 = Y - H / 2.0f;
    float x2 = X + W / 2.0f, y2 = Y + H / 2.0f;
    boxd4[b] = make_float4(x1, y1, x2, y2);
    meta[2 * b] = conf;
    ((int*)meta)[2 * b + 1] = cls;
  }
}

// ---------------- NMS stage 1: zero keep + compact + sort -> sorted arrays ----------------
__global__ __launch_bounds__(256) void k_nms_sort(const float4* __restrict__ boxd4,
    const float* __restrict__ meta, int* __restrict__ cnt,
    float4* __restrict__ sbf, int* __restrict__ sidx, float* __restrict__ keep_out) {
  __shared__ unsigned long long key[8192];
  __shared__ int scnt;
  int bid = blockIdx.x;  // 0..23
  int n = bid / 3, c = bid - n * 3;
  int tid = threadIdx.x;
  float* ko = keep_out + (size_t)bid * 4800;
  for (int s = tid; s < 4800; s += 256) ko[s] = 0.f;
  if (tid == 0) scnt = 0;
  __syncthreads();

  const float* mt = meta + (size_t)n * 9600;
  for (int p = tid; p < 4800; p += 256) {
    float2 m = ((const float2*)mt)[p];
    float conf = m.x;
    int cls = __float_as_int(m.y);
    if (conf > 0.5f && cls == c) {
      int slot = atomicAdd(&scnt, 1);
      unsigned u = __float_as_uint(conf);
      unsigned asc = (u & 0x80000000u) ? ~u : (u | 0x80000000u);
      key[slot] = (((unsigned long long)(~asc)) << 32) | (unsigned)p;
    }
  }
  __syncthreads();
  int V = scnt;
  if (tid == 0) cnt[bid] = V;
  if (V == 0) return;
  int Vp2 = 1;
  while (Vp2 < V) Vp2 <<= 1;
  for (int s = V + tid; s < Vp2; s += 256) key[s] = ~0ull;

  for (int k = 2; k <= Vp2; k <<= 1) {
    for (int j = k >> 1; j > 0; j >>= 1) {
      __syncthreads();
      int jm = j - 1;
      for (int t2 = tid; t2 < (Vp2 >> 1); t2 += 256) {
        int i = ((t2 & ~jm) << 1) | (t2 & jm);
        int q = i | j;
        bool up = ((i & k) == 0);
        unsigned long long a = key[i], b2 = key[q];
        if ((a > b2) == up) { key[i] = b2; key[q] = a; }
      }
    }
  }
  __syncthreads();
  float4* sb = sbf + (size_t)bid * 4800;
  int* si = sidx + (size_t)bid * 4800;
  const float4* bsrc = boxd4 + (size_t)n * 4800;
  for (int s = tid; s < V; s += 256) {
    unsigned p = (unsigned)(key[s] & 0xFFFFFFFFull);
    sb[s] = bsrc[p];
    si[s] = (int)p;
  }
}

// ---------------- NMS stage 2: grid-parallel suppression bit-matrix ----------------
__global__ __launch_bounds__(256) void k_iou_mat(const int* __restrict__ cnt,
    const float4* __restrict__ sbf, unsigned long long* __restrict__ mat) {
  int nc = blockIdx.x;
  int w = blockIdx.y;
  int V = cnt[nc];
  if (V == 0 || V > 1024) return;
  int W = (V + 63) >> 6;
  if (w >= W) return;
  int tid = threadIdx.x;
  int l = tid & 63, wv = tid >> 6;
  const float4* sb = sbf + (size_t)nc * 4800;
  int col = (w << 6) + l;
  float4 bj = sb[col < V ? col : (V - 1)];
  float aj = (bj.z - bj.x + 1.0f) * (bj.w - bj.y + 1.0f);
  unsigned long long* mrow = mat + (size_t)nc * 1024 * 16 + w;
  for (int i = wv; i < V; i += 4) {
    float4 bi = sb[i];  // wave-uniform, L2-hot
    float iw = fminf(bi.z, bj.z) - fmaxf(bi.x, bj.x) + 1.0f;
    float ih = fminf(bi.w, bj.w) - fmaxf(bi.y, bj.y) + 1.0f;
    iw = fmaxf(iw, 0.f);
    ih = fmaxf(ih, 0.f);
    float inter = iw * ih;
    float ai = (bi.z - bi.x + 1.0f) * (bi.w - bi.y + 1.0f);
    float iou = inter / (ai + aj - inter);
    bool pr = (col > i) && (col < V) && (iou >= 0.4f);
    unsigned long long word = __ballot(pr);
    if (l == 0) mrow[(size_t)i * 16] = word;
  }
}

// ---------------- NMS stage 3: linear greedy scan, VALU-only serial chain ----------------
__global__ __launch_bounds__(256) void k_nms_scan(const int* __restrict__ cnt,
    const unsigned long long* __restrict__ mat, const float4* __restrict__ sbf,
    const int* __restrict__ sidx, float* __restrict__ keep_out) {
  __shared__ float4 sbL[4800];            // slow-path staging
  __shared__ unsigned long long avail[75];
  int nc = blockIdx.x;
  int V = cnt[nc];
  if (V == 0) return;
  int tid = threadIdx.x;
  float* ko = keep_out + (size_t)nc * 4800;
  const int* si = sidx + (size_t)nc * 4800;

  if (V <= 1024) {
    if (tid >= 64) return;
    int l = tid;
    int W = (V + 63) >> 6;
    const unsigned long long* mbase = mat + (size_t)nc * 1024 * 16;
    bool act = (l < W);
    unsigned long long av = 0ull;  // lane l holds avail word l
    if (act) {
      int rem = V - (l << 6);
      av = (rem >= 64) ? ~0ull : ((1ull << rem) - 1ull);
    }
    unsigned long long mA[16], mB[16];
#pragma unroll
    for (int k = 0; k < 16; k++)
      mA[k] = (act && k < V) ? mbase[(size_t)k * 16 + l] : 0ull;
    for (int i0 = 0; i0 < V; i0 += 16) {
      int nx = i0 + 16;
#pragma unroll
      for (int k = 0; k < 16; k++)
        mB[k] = (act && (nx + k) < V) ? mbase[(size_t)(nx + k) * 16 + l] : 0ull;
      int wi = i0 >> 6;
      unsigned long long mloc[16];
#pragma unroll
      for (int k = 0; k < 16; k++) mloc[k] = __shfl(mA[k], wi, 64);
      unsigned long long cur = __shfl(av, wi, 64);
      unsigned alive = 0;
#pragma unroll
      for (int k = 0; k < 16; k++) {
        int i = i0 + k;
        if (i < V && ((cur >> (i & 63)) & 1ull)) {
          alive |= 1u << k;
          cur &= ~mloc[k];
        }
      }
#pragma unroll
      for (int k = 0; k < 16; k++)
        if ((alive >> k) & 1u) av &= ~mA[k];
      if (l < 16 && ((alive >> l) & 1u) && (i0 + l) < V) ko[si[i0 + l]] = 1.0f;
#pragma unroll
      for (int k = 0; k < 16; k++) mA[k] = mB[k];
    }
    return;
  }

  // slow path (V > 1024): r6-validated single-wave greedy
  {
    const float4* sb = sbf + (size_t)nc * 4800;
    for (int s = tid; s < V; s += 256) sbL[s] = sb[s];
    for (int w = tid; w < 75; w += 256) {
      int rem = V - (w << 6);
      avail[w] = (rem >= 64) ? ~0ull : (rem <= 0 ? 0ull : ((1ull << rem) - 1ull));
    }
    __syncthreads();
    if (tid >= 64) return;
    int l = tid;
    int wlast = (V - 1) >> 6;
    for (;;) {
      int cand = 0x7FFFFFFF;
      unsigned long long a0 = avail[l];
      if (a0) cand = (l << 6) + __ffsll((long long)a0) - 1;
      if (l < 11) {
        unsigned long long a1 = avail[64 + l];
        if (a1) {
          int c2 = ((64 + l) << 6) + __ffsll((long long)a1) - 1;
          if (c2 < cand) cand = c2;
        }
      }
#pragma unroll
      for (int off = 32; off > 0; off >>= 1) {
        int o = __shfl_xor(cand, off, 64);
        if (o < cand) cand = o;
      }
      if (cand == 0x7FFFFFFF) break;
      int i = cand;
      int tw = i >> 6;
      if (l == 0) {
        ko[si[i]] = 1.0f;
        avail[tw] &= ~(1ull << (i & 63));
      }
      float4 bi = sbL[i];
      float ai = (bi.z - bi.x + 1.0f) * (bi.w - bi.y + 1.0f);
      for (int w = tw; w <= wlast; w++) {
        unsigned long long aw = avail[w];
        if (!aw) continue;
        int col = (w << 6) + l;
        float4 bj = sbL[col];
        float iw = fminf(bi.z, bj.z) - fmaxf(bi.x, bj.x) + 1.0f;
        float ih = fminf(bi.w, bj.w) - fmaxf(bi.y, bj.y) + 1.0f;
        iw = fmaxf(iw, 0.f);
        ih = fmaxf(ih, 0.f);
        float inter = iw * ih;
        float aj = (bj.z - bj.x + 1.0f) * (bj.w - bj.y + 1.0f);
        float iou = inter / (ai + aj - inter);
        bool pr = (col > i) && (col < V) && (iou >= 0.4f);
        unsigned long long word = __ballot(pr);
        if (word && l == 0) avail[w] = aw & ~word;
      }
    }
  }
}

extern "C" void kernel_launch(void* const* d_in, const int* in_sizes, int n_in,
                              void* d_out, int out_size, void* d_ws, size_t ws_size,
                              hipStream_t stream) {
  const float* img = (const float*)d_in[0];
  const float* w1 = (const float*)d_in[1];
  const float* b1 = (const float*)d_in[2];
  const float* w2 = (const float*)d_in[3];
  const float* b2 = (const float*)d_in[4];
  const float* w3 = (const float*)d_in[5];
  const float* b3 = (const float*)d_in[6];
  const float* wd1 = (const float*)d_in[7];
  const float* bd1 = (const float*)d_in[8];
  const float* wd2 = (const float*)d_in[9];
  const float* bd2 = (const float*)d_in[10];

  float* ws = (float*)d_ws;
  float* a3 = ws + 0;                       // 1,971,200
  float* pd1 = ws + 3942400;                // 1,972,224 (dead after reduce1a)
  float* partr = ws + 5914624;              // 32,768
  float4* boxd4 = (float4*)(ws + 5947392);  // 153,600 floats
  float* meta = ws + 6100992;               // 76,800
  float4* sbf = (float4*)(ws + 6177792);    // 460,800
  int* sidx = (int*)(ws + 6638592);         // 115,200
  int* cnt = (int*)(ws + 6753792);          // 24
  float* p1 = ws + 9324800;                 // 2,306,304 pooled conv1
  float* p2 = ws + 16047104;                // 1,079,808 pooled conv2
  unsigned long long* mat = (unsigned long long*)(ws + 3942400);  // overlays pd1

  float* pred = (float*)d_out;
  float* keep = pred + 307200;

  k_conv1p<<<dim3(8, 10, 8), 256, 0, stream>>>(img, w1, b1, p1);
  k_conv2p<<<dim3(8, 10, 8), 256, 0, stream>>>(p1, w2, b2, p2);
  k_conv3<<<dim3(4, 9, 16), 256, 0, stream>>>(p2, w3, b3, a3);
  k_dense1<<<963, 256, 0, stream>>>(a3, wd1, pd1);
  k_reduce1a<<<dim3(16, 8), 256, 0, stream>>>(pd1, partr);
  k_dense2t<<<300, 256, 0, stream>>>(partr, bd1, wd2, bd2, pred, boxd4, meta);
  k_nms_sort<<<24, 256, 0, stream>>>(boxd4, meta, cnt, sbf, sidx, keep);
  k_iou_mat<<<dim3(24, 16), 256, 0, stream>>>(cnt, sbf, mat);
  k_nms_scan<<<24, 256, 0, stream>>>(cnt, mat, sbf, sidx, keep);
}